// Round 4
// baseline (150.942 us; speedup 1.0000x reference)
//
#include <hip/hip_runtime.h>

#define NQ 9
#define NS 512            // 2^9 amplitudes
#define M2 1024           // [Re V; Im V] stacked rows

#define COEF_ROT_BASE (72*32)                 // 72 ent steps x 32 floats
#define COEF_FLOATS   (COEF_ROT_BASE + 27*8)  // + 27 rots x 8 floats = 2520

typedef __attribute__((ext_vector_type(8))) short bf16x8;
typedef __attribute__((ext_vector_type(4))) float f32x4;

__device__ inline unsigned short f2bf(float f){
  unsigned int u = __float_as_uint(f);
  u += 0x7fffu + ((u >> 16) & 1u);   // round-to-nearest-even
  return (unsigned short)(u >> 16);
}

// =====================  coefficient precompute (tiny kernel)  =====================
// Ent step g (g = blk*9 + I): fused 4x4 complex G = L(th2,th3) * (RY(th0) (x) RY(th1))
// stored as Gx[4][4] then Gy[4][4] at coef[g*32].
// Rot r (r = layer*9 + wire): u00,u01,u10,u11 (complex) at coef[COEF_ROT_BASE + r*8].
__global__ __launch_bounds__(128) void precoef(const float* __restrict__ params,
                                               const float* __restrict__ weights,
                                               const float* __restrict__ params2,
                                               float* __restrict__ coef){
  int tid = threadIdx.x;
  if (tid < 72){
    int blk = tid / 9, I = tid % 9;
    const float* p = (blk < 3) ? params + blk*36 : params2 + (blk-3)*36;
    float s0,c0,s1,c1,s2,c2,s3,c3;
    __sincosf(0.5f*p[4*I+0], &s0, &c0);
    __sincosf(0.5f*p[4*I+1], &s1, &c1);
    __sincosf(0.5f*p[4*I+2], &s2, &c2);
    __sincosf(0.5f*p[4*I+3], &s3, &c3);
    // M1 = RY(th0) (x) RY(th1), real
    float m[4][4] = {
      { c0*c1, -c0*s1, -s0*c1,  s0*s1},
      { c0*s1,  c0*c1, -s0*s1, -s0*c1},
      { s0*c1, -s0*s1,  c0*c1, -c0*s1},
      { s0*s1,  s0*c1,  c0*s1,  c0*c1}};
    float gx[4][4], gy[4][4];
    #pragma unroll
    for (int q = 0; q < 4; ++q){
      gx[0][q] = m[1][q];  gy[0][q] = 0.f;      // row swap from X(q1)
      gx[1][q] = m[0][q];  gy[1][q] = 0.f;
      gx[2][q] =  c3*c2*m[2][q] - s3*s2*m[3][q];
      gy[2][q] =  c3*s2*m[2][q] - s3*c2*m[3][q];
      gx[3][q] =  s3*s2*m[2][q] + c3*c2*m[3][q];
      gy[3][q] = -(s3*c2*m[2][q] + c3*s2*m[3][q]);
    }
    float* dst = coef + tid*32;
    #pragma unroll
    for (int r = 0; r < 4; ++r)
      #pragma unroll
      for (int q = 0; q < 4; ++q){
        dst[r*4+q]      = gx[r][q];
        dst[16+r*4+q]   = gy[r][q];
      }
  } else if (tid < 99){
    int r = tid - 72;
    int l = r / 9, i = r % 9;
    const float* w = weights + l*27 + 3*i;
    float phi = w[0], th = w[1], om = w[2];
    float sT,cT,sA,cA,sB,cB;
    __sincosf(0.5f*th, &sT, &cT);
    __sincosf(0.5f*(phi+om), &sA, &cA);
    __sincosf(0.5f*(om-phi), &sB, &cB);
    float* dst = coef + COEF_ROT_BASE + r*8;
    dst[0] =  cA*cT;  dst[1] = -sA*cT;   // u00
    dst[2] = -cB*sT;  dst[3] =  sB*sT;   // u01
    dst[4] =  cB*sT;  dst[5] =  sB*sT;   // u10
    dst[6] =  cA*cT;  dst[7] =  sA*cT;   // u11
  }
}

// =====================  2-wave register-resident statevector sim  =====================
// One block (2 waves, 128 thr) per column t. Amp index (9 bits):
//   bit 8 -> wave, bits 2-7 -> lane bits 0-5, bits 0-1 -> reg j.
// Wire w <-> bit (8-w).

template<int LM>
__device__ inline float lxor(float v){
  if constexpr (LM == 1)
    return __int_as_float(__builtin_amdgcn_mov_dpp(__float_as_int(v), 0xB1, 0xF, 0xF, true));
  else if constexpr (LM == 2)
    return __int_as_float(__builtin_amdgcn_mov_dpp(__float_as_int(v), 0x4E, 0xF, 0xF, true));
  else if constexpr (LM == 3)
    return __int_as_float(__builtin_amdgcn_mov_dpp(__float_as_int(v), 0x1B, 0xF, 0xF, true));
  else if constexpr (LM < 32)
    return __int_as_float(__builtin_amdgcn_ds_swizzle(__float_as_int(v), (LM<<10)|0x1F));
  else
    return __shfl_xor(v, LM);
}

// cross-wave exchange of all 4 complex amps
__device__ inline void wexch(float2* sh, int wv, int lane,
                             const float ax[4], const float ay[4],
                             float px[4], float py[4]){
  __syncthreads();
  #pragma unroll
  for (int j = 0; j < 4; ++j) sh[j*128 + (wv<<6) + lane] = make_float2(ax[j], ay[j]);
  __syncthreads();
  #pragma unroll
  for (int j = 0; j < 4; ++j){
    float2 p = sh[j*128 + ((wv^1)<<6) + lane];
    px[j] = p.x; py[j] = p.y;
  }
}

// h_d = G[p][p^d], p = (cb<<1)|tb, selected per lane
__device__ inline void hsel(const float* __restrict__ G, bool cb, bool tb,
                            float hx[4], float hy[4]){
  const float* Gx = G; const float* Gy = G + 16;
  #pragma unroll
  for (int d = 0; d < 4; ++d){
    float xa = tb ? Gx[4+(1^d)]  : Gx[d];
    float xb = tb ? Gx[12+(3^d)] : Gx[8+(2^d)];
    float ya = tb ? Gy[4+(1^d)]  : Gy[d];
    float yb = tb ? Gy[12+(3^d)] : Gy[8+(2^d)];
    hx[d] = cb ? xb : xa;
    hy[d] = cb ? yb : ya;
  }
}

__device__ inline void cfma(float& nx, float& ny, float hx, float hy, float vx, float vy){
  nx += hx*vx - hy*vy;
  ny += hx*vy + hy*vx;
}

// both wires in lane bits
template<int LC, int LT>
__device__ inline void step_ll(float ax[4], float ay[4], int lane, const float* __restrict__ G){
  float hx[4], hy[4];
  hsel(G, (lane & LC) != 0, (lane & LT) != 0, hx, hy);
  #pragma unroll
  for (int j = 0; j < 4; ++j){
    float ox = ax[j], oy = ay[j];
    float tx = lxor<LT>(ox),      ty = lxor<LT>(oy);
    float cx = lxor<LC>(ox),      cy = lxor<LC>(oy);
    float bx = lxor<(LC^LT)>(ox), by = lxor<(LC^LT)>(oy);
    float nx = 0.f, ny = 0.f;
    cfma(nx,ny,hx[0],hy[0],ox,oy);
    cfma(nx,ny,hx[1],hy[1],tx,ty);
    cfma(nx,ny,hx[2],hy[2],cx,cy);
    cfma(nx,ny,hx[3],hy[3],bx,by);
    ax[j] = nx; ay[j] = ny;
  }
}

// ctrl = wave bit, target = lane bit 5  (ent step I=0)
__device__ inline void step_wl(float ax[4], float ay[4], int lane, int wv,
                               float2* sh, const float* __restrict__ G){
  float pwx[4], pwy[4];
  wexch(sh, wv, lane, ax, ay, pwx, pwy);
  float hx[4], hy[4];
  hsel(G, wv != 0, (lane & 32) != 0, hx, hy);
  #pragma unroll
  for (int j = 0; j < 4; ++j){
    float ox = ax[j], oy = ay[j];
    float tx = lxor<32>(ox),     ty = lxor<32>(oy);
    float cx = pwx[j],           cy = pwy[j];
    float bx = lxor<32>(cx),     by = lxor<32>(cy);
    float nx = 0.f, ny = 0.f;
    cfma(nx,ny,hx[0],hy[0],ox,oy);
    cfma(nx,ny,hx[1],hy[1],tx,ty);
    cfma(nx,ny,hx[2],hy[2],cx,cy);
    cfma(nx,ny,hx[3],hy[3],bx,by);
    ax[j] = nx; ay[j] = ny;
  }
}

// ctrl = lane bit 0, target = reg bit 1  (ent step I=6)
__device__ inline void step_lr(float ax[4], float ay[4], int lane, const float* __restrict__ G){
  const float* Gx = G; const float* Gy = G + 16;
  bool cb = (lane & 1) != 0;
  float hx[2][4], hy[2][4];
  #pragma unroll
  for (int tb = 0; tb < 2; ++tb)
    #pragma unroll
    for (int d = 0; d < 4; ++d){
      int p0 = tb, p1 = 2|tb;
      hx[tb][d] = cb ? Gx[p1*4+(p1^d)] : Gx[p0*4+(p0^d)];
      hy[tb][d] = cb ? Gy[p1*4+(p1^d)] : Gy[p0*4+(p0^d)];
    }
  float nax[4], nay[4];
  #pragma unroll
  for (int j = 0; j < 4; ++j){
    int tb = (j>>1)&1, jt = j^2;
    float ox = ax[j],  oy = ay[j];
    float tx = ax[jt], ty = ay[jt];
    float cx = lxor<1>(ox), cy = lxor<1>(oy);
    float bx = lxor<1>(tx), by = lxor<1>(ty);
    float nx = 0.f, ny = 0.f;
    cfma(nx,ny,hx[tb][0],hy[tb][0],ox,oy);
    cfma(nx,ny,hx[tb][1],hy[tb][1],tx,ty);
    cfma(nx,ny,hx[tb][2],hy[tb][2],cx,cy);
    cfma(nx,ny,hx[tb][3],hy[tb][3],bx,by);
    nax[j] = nx; nay[j] = ny;
  }
  #pragma unroll
  for (int j = 0; j < 4; ++j){ ax[j] = nax[j]; ay[j] = nay[j]; }
}

// both wires in reg bits: ctrl bit1, target bit0  (ent step I=7); p == j
__device__ inline void step_rr(float ax[4], float ay[4], const float* __restrict__ G){
  const float* Gx = G; const float* Gy = G + 16;
  float nax[4], nay[4];
  #pragma unroll
  for (int p = 0; p < 4; ++p){
    float nx = 0.f, ny = 0.f;
    #pragma unroll
    for (int q = 0; q < 4; ++q)
      cfma(nx,ny,Gx[p*4+q],Gy[p*4+q],ax[q],ay[q]);
    nax[p] = nx; nay[p] = ny;
  }
  #pragma unroll
  for (int j = 0; j < 4; ++j){ ax[j] = nax[j]; ay[j] = nay[j]; }
}

// ctrl = reg bit 0, target = wave bit  (ent step I=8)
__device__ inline void step_rw(float ax[4], float ay[4], int lane, int wv,
                               float2* sh, const float* __restrict__ G){
  float pwx[4], pwy[4];
  wexch(sh, wv, lane, ax, ay, pwx, pwy);
  const float* Gx = G; const float* Gy = G + 16;
  bool tb = wv != 0;
  float hx[2][4], hy[2][4];
  #pragma unroll
  for (int cb = 0; cb < 2; ++cb)
    #pragma unroll
    for (int d = 0; d < 4; ++d){
      int p0 = cb<<1, p1 = (cb<<1)|1;
      hx[cb][d] = tb ? Gx[p1*4+(p1^d)] : Gx[p0*4+(p0^d)];
      hy[cb][d] = tb ? Gy[p1*4+(p1^d)] : Gy[p0*4+(p0^d)];
    }
  float nax[4], nay[4];
  #pragma unroll
  for (int j = 0; j < 4; ++j){
    int cb = j & 1;
    float ox = ax[j],   oy = ay[j];
    float tx = pwx[j],  ty = pwy[j];
    float cx = ax[j^1], cy = ay[j^1];
    float bx = pwx[j^1], by = pwy[j^1];
    float nx = 0.f, ny = 0.f;
    cfma(nx,ny,hx[cb][0],hy[cb][0],ox,oy);
    cfma(nx,ny,hx[cb][1],hy[cb][1],tx,ty);
    cfma(nx,ny,hx[cb][2],hy[cb][2],cx,cy);
    cfma(nx,ny,hx[cb][3],hy[cb][3],bx,by);
    nax[j] = nx; nay[j] = ny;
  }
  #pragma unroll
  for (int j = 0; j < 4; ++j){ ax[j] = nax[j]; ay[j] = nay[j]; }
}

// ---- Rot (1-qubit complex 2x2), coefs u[8] = u00,u01,u10,u11 (x,y pairs) ----
template<int LM>
__device__ inline void rot_l(float ax[4], float ay[4], int lane, const float* __restrict__ u){
  bool hi = (lane & LM) != 0;
  float cax = hi?u[6]:u[0], cay = hi?u[7]:u[1];
  float cbx = hi?u[4]:u[2], cby = hi?u[5]:u[3];
  #pragma unroll
  for (int j = 0; j < 4; ++j){
    float ox = ax[j], oy = ay[j];
    float px = lxor<LM>(ox), py = lxor<LM>(oy);
    ax[j] = cax*ox - cay*oy + cbx*px - cby*py;
    ay[j] = cax*oy + cay*ox + cbx*py + cby*px;
  }
}

template<int M>
__device__ inline void rot_r(float ax[4], float ay[4], const float* __restrict__ u){
  #pragma unroll
  for (int j0 = 0; j0 < 4; ++j0) if (!(j0 & M)){
    int j1 = j0 | M;
    float x0=ax[j0], y0=ay[j0], x1=ax[j1], y1=ay[j1];
    ax[j0] = u[0]*x0 - u[1]*y0 + u[2]*x1 - u[3]*y1;
    ay[j0] = u[0]*y0 + u[1]*x0 + u[2]*y1 + u[3]*x1;
    ax[j1] = u[4]*x0 - u[5]*y0 + u[6]*x1 - u[7]*y1;
    ay[j1] = u[4]*y0 + u[5]*x0 + u[6]*y1 + u[7]*x1;
  }
}

__device__ inline void rot_w(float ax[4], float ay[4], int lane, int wv, float2* sh,
                             const float* __restrict__ u){
  float pwx[4], pwy[4];
  wexch(sh, wv, lane, ax, ay, pwx, pwy);
  bool hi = wv != 0;
  float cax = hi?u[6]:u[0], cay = hi?u[7]:u[1];
  float cbx = hi?u[4]:u[2], cby = hi?u[5]:u[3];
  #pragma unroll
  for (int j = 0; j < 4; ++j){
    float ox = ax[j], oy = ay[j], px = pwx[j], py = pwy[j];
    ax[j] = cax*ox - cay*oy + cbx*px - cby*py;
    ay[j] = cax*oy + cay*ox + cbx*py + cby*px;
  }
}

// CNOT ring of range R: one LDS permutation round-trip.
// src index = apply CNOT(i, i+R) for i = 8..0 (self-inverse gates, reversed order).
template<int R>
__device__ inline void ring(float ax[4], float ay[4], int lane, int wv, float2* sh){
  __syncthreads();
  int base = (wv<<8) | (lane<<2);
  #pragma unroll
  for (int j = 0; j < 4; ++j) sh[base+j] = make_float2(ax[j], ay[j]);
  __syncthreads();
  #pragma unroll
  for (int j = 0; j < 4; ++j){
    int s = base + j;
    #pragma unroll
    for (int i = 8; i >= 0; --i){
      int bc = 8 - i, bt = 8 - ((i + R) % 9);
      s ^= ((s >> bc) & 1) << bt;
    }
    float2 v = sh[s];
    ax[j] = v.x; ay[j] = v.y;
  }
}

// ---------------- compile-time drivers ----------------

template<int BLK, int I = 0>
__device__ inline void ent_block(float ax[4], float ay[4], int lane, int wv, float2* sh,
                                 const float* __restrict__ coef){
  const float* G = coef + (BLK*9 + I)*32;
  if constexpr      (I == 0) step_wl(ax, ay, lane, wv, sh, G);
  else if constexpr (I == 1) step_ll<32,16>(ax, ay, lane, G);
  else if constexpr (I == 2) step_ll<16, 8>(ax, ay, lane, G);
  else if constexpr (I == 3) step_ll< 8, 4>(ax, ay, lane, G);
  else if constexpr (I == 4) step_ll< 4, 2>(ax, ay, lane, G);
  else if constexpr (I == 5) step_ll< 2, 1>(ax, ay, lane, G);
  else if constexpr (I == 6) step_lr(ax, ay, lane, G);
  else if constexpr (I == 7) step_rr(ax, ay, G);
  else                       step_rw(ax, ay, lane, wv, sh, G);
  if constexpr (I < 8) ent_block<BLK, I+1>(ax, ay, lane, wv, sh, coef);
}

template<int L, int I = 0>
__device__ inline void sel_rots(float ax[4], float ay[4], int lane, int wv, float2* sh,
                                const float* __restrict__ coef){
  const float* u = coef + COEF_ROT_BASE + (L*9 + I)*8;
  if constexpr      (I == 0) rot_w(ax, ay, lane, wv, sh, u);
  else if constexpr (I == 1) rot_l<32>(ax, ay, lane, u);
  else if constexpr (I == 2) rot_l<16>(ax, ay, lane, u);
  else if constexpr (I == 3) rot_l< 8>(ax, ay, lane, u);
  else if constexpr (I == 4) rot_l< 4>(ax, ay, lane, u);
  else if constexpr (I == 5) rot_l< 2>(ax, ay, lane, u);
  else if constexpr (I == 6) rot_l< 1>(ax, ay, lane, u);
  else if constexpr (I == 7) rot_r< 2>(ax, ay, u);
  else                       rot_r< 1>(ax, ay, u);
  if constexpr (I < 8) sel_rots<L, I+1>(ax, ay, lane, wv, sh, coef);
}

__global__ __launch_bounds__(128) void sim_V(const float* __restrict__ coef,
                                             unsigned short* __restrict__ A2){
  __shared__ float2 sh[512];
  int t = blockIdx.x;
  int wv = threadIdx.x >> 6, lane = threadIdx.x & 63;
  float ax[4], ay[4];
  int pc = __popc((unsigned)t) & 3;
  float prx = (pc==0) ? 1.f : (pc==2 ? -1.f : 0.f);
  float pry = (pc==3) ? 1.f : (pc==1 ? -1.f : 0.f);
  int wv_t = t >> 8, ln_t = (t >> 2) & 63, j_t = t & 3;
  #pragma unroll
  for (int j = 0; j < 4; ++j){
    bool hit = (wv == wv_t) && (lane == ln_t) && (j == j_t);
    ax[j] = hit ? prx : 0.f;
    ay[j] = hit ? pry : 0.f;
  }
  ent_block<0>(ax, ay, lane, wv, sh, coef);
  ent_block<1>(ax, ay, lane, wv, sh, coef);
  ent_block<2>(ax, ay, lane, wv, sh, coef);
  sel_rots<0>(ax, ay, lane, wv, sh, coef);  ring<1>(ax, ay, lane, wv, sh);
  sel_rots<1>(ax, ay, lane, wv, sh, coef);  ring<2>(ax, ay, lane, wv, sh);
  sel_rots<2>(ax, ay, lane, wv, sh, coef);  ring<3>(ax, ay, lane, wv, sh);
  ent_block<3>(ax, ay, lane, wv, sh, coef);
  ent_block<4>(ax, ay, lane, wv, sh, coef);
  ent_block<5>(ax, ay, lane, wv, sh, coef);
  ent_block<6>(ax, ay, lane, wv, sh, coef);
  ent_block<7>(ax, ay, lane, wv, sh, coef);

  int sbase = (wv << 8) | (lane << 2);
  #pragma unroll
  for (int j = 0; j < 4; ++j){
    int s = sbase + j;
    A2[(size_t)s * NS + t]        = f2bf(ax[j]);
    A2[(size_t)(s + NS) * NS + t] = f2bf(ay[j]);
  }
}

// build_c (wave per sample, coalesced 16B stores) + zero the output accumulator
__global__ __launch_bounds__(256) void prep(const float* __restrict__ adds,
                                            unsigned short* __restrict__ cT,
                                            float* __restrict__ out, int B){
  int gid = blockIdx.x * 256 + threadIdx.x;
  int b = gid >> 6;
  int lane = gid & 63;
  if (b < B){
    const float* ab = adds + b * NQ;
    float cw[NQ], sw[NQ];
    #pragma unroll
    for (int w = 0; w < NQ; ++w)
      __sincosf(0.5f * ab[w], &sw[w], &cw[w]);
    float p6 = 1.f;
    #pragma unroll
    for (int w = 0; w < 6; ++w)
      p6 *= ((lane >> (5 - w)) & 1) ? sw[w] : cw[w];
    union { unsigned short u[8]; uint4 v; } pk;
    #pragma unroll
    for (int j = 0; j < 8; ++j){
      float p = p6 * (((j>>2)&1) ? sw[6] : cw[6])
                   * (((j>>1)&1) ? sw[7] : cw[7])
                   * (( j    &1) ? sw[8] : cw[8]);
      pk.u[j] = f2bf(p);
    }
    *(uint4*)(cT + (size_t)b * NS + lane*8) = pk.v;
  }
  if (gid < B) out[gid] = 0.f;
}

// Phi2 = A2(1024x512) @ c(512xB); out[b] = sum_row sign(row) * Phi2[row][b]^2,
// sign(row) = -1 iff (row & 256).
__global__ __launch_bounds__(256) void gemm_out(const unsigned short* __restrict__ A2,
                                                const unsigned short* __restrict__ cT,
                                                float* __restrict__ out){
  int bx = blockIdx.x;            // N tile (128 cols of b)
  int by = blockIdx.y;            // M tile (128 rows), 8 tiles
  int tid = threadIdx.x;
  int wave = tid >> 6, lane = tid & 63;
  int wy = wave >> 1, wx = wave & 1;
  int lane15 = lane & 15, quad = lane >> 4;
  int rowBase = by*128 + wy*64;
  int colBase = bx*128 + wx*64;
  const short* Ap = (const short*)A2;   // [row][k]
  const short* Bp = (const short*)cT;   // [col][k]

  f32x4 acc[4][4];
  #pragma unroll
  for (int i = 0; i < 4; ++i)
    #pragma unroll
    for (int j = 0; j < 4; ++j)
      acc[i][j] = (f32x4){0.f, 0.f, 0.f, 0.f};

  #pragma unroll 2
  for (int k0 = 0; k0 < NS; k0 += 32){
    bf16x8 a[4], b[4];
    #pragma unroll
    for (int mi = 0; mi < 4; ++mi)
      a[mi] = *(const bf16x8*)(Ap + (size_t)(rowBase + mi*16 + lane15)*NS + k0 + quad*8);
    #pragma unroll
    for (int ni = 0; ni < 4; ++ni)
      b[ni] = *(const bf16x8*)(Bp + (size_t)(colBase + ni*16 + lane15)*NS + k0 + quad*8);
    #pragma unroll
    for (int mi = 0; mi < 4; ++mi)
      #pragma unroll
      for (int ni = 0; ni < 4; ++ni)
        acc[mi][ni] = __builtin_amdgcn_mfma_f32_16x16x32_bf16(a[mi], b[ni], acc[mi][ni], 0, 0, 0);
  }

  float sign = (by & 2) ? -1.f : 1.f;
  #pragma unroll
  for (int ni = 0; ni < 4; ++ni){
    float cs = 0.f;
    #pragma unroll
    for (int mi = 0; mi < 4; ++mi)
      #pragma unroll
      for (int r = 0; r < 4; ++r)
        cs += acc[mi][ni][r] * acc[mi][ni][r];
    cs += __shfl_xor(cs, 16);
    cs += __shfl_xor(cs, 32);
    if (quad == 0)
      atomicAdd(out + colBase + ni*16 + lane15, sign * cs);
  }
}

extern "C" void kernel_launch(void* const* d_in, const int* in_sizes, int n_in,
                              void* d_out, int out_size, void* d_ws, size_t ws_size,
                              hipStream_t stream) {
  const float* adds    = (const float*)d_in[0];
  const float* params  = (const float*)d_in[1];
  const float* weights = (const float*)d_in[2];
  const float* params2 = (const float*)d_in[3];
  float* out = (float*)d_out;
  int B = in_sizes[0] / NQ;   // 8192

  unsigned short* A2 = (unsigned short*)d_ws;        // 1024*512 bf16 = 1 MB
  unsigned short* cT = A2 + (size_t)M2 * NS;         // B*512 bf16 = 8 MB
  size_t base = (size_t)M2*NS*2 + (size_t)B*NS*2;    // 9 MB
  // coef buffer: prefer workspace tail; fall back to d_out (read before prep zeroes it)
  float* coef = (ws_size >= base + COEF_FLOATS*sizeof(float))
              ? (float*)((char*)d_ws + base)
              : (float*)d_out;

  hipLaunchKernelGGL(precoef, dim3(1), dim3(128), 0, stream, params, weights, params2, coef);
  hipLaunchKernelGGL(sim_V, dim3(NS), dim3(128), 0, stream, coef, A2);
  hipLaunchKernelGGL(prep, dim3((B * 64 + 255) / 256), dim3(256), 0, stream, adds, cT, out, B);
  hipLaunchKernelGGL(gemm_out, dim3(B / 128, 8), dim3(256), 0, stream, A2, cT, out);
}

// Round 5
// 141.327 us; speedup vs baseline: 1.0680x; 1.0680x over previous
//
#include <hip/hip_runtime.h>

#define NQ 9
#define NS 512            // 2^9 amplitudes
#define M2 1024           // [Re V; Im V] stacked rows

#define COEF_ROT_BASE (72*32)                 // 72 ent steps x 32 floats
#define COEF_FLOATS   (COEF_ROT_BASE + 27*8)  // + 27 rots x 8 floats = 2520
#define COEF_PAD      2560                    // padded to /4 and /128

typedef __attribute__((ext_vector_type(8))) short bf16x8;
typedef __attribute__((ext_vector_type(4))) float f32x4;

__device__ inline unsigned short f2bf(float f){
  unsigned int u = __float_as_uint(f);
  u += 0x7fffu + ((u >> 16) & 1u);   // round-to-nearest-even
  return (unsigned short)(u >> 16);
}

// =====================  coefficient precompute (tiny kernel)  =====================
__global__ __launch_bounds__(128) void precoef(const float* __restrict__ params,
                                               const float* __restrict__ weights,
                                               const float* __restrict__ params2,
                                               float* __restrict__ coef){
  int tid = threadIdx.x;
  if (tid < 72){
    int blk = tid / 9, I = tid % 9;
    const float* p = (blk < 3) ? params + blk*36 : params2 + (blk-3)*36;
    float s0,c0,s1,c1,s2,c2,s3,c3;
    __sincosf(0.5f*p[4*I+0], &s0, &c0);
    __sincosf(0.5f*p[4*I+1], &s1, &c1);
    __sincosf(0.5f*p[4*I+2], &s2, &c2);
    __sincosf(0.5f*p[4*I+3], &s3, &c3);
    // M1 = RY(th0) (x) RY(th1), real
    float m[4][4] = {
      { c0*c1, -c0*s1, -s0*c1,  s0*s1},
      { c0*s1,  c0*c1, -s0*s1, -s0*c1},
      { s0*c1, -s0*s1,  c0*c1, -c0*s1},
      { s0*s1,  s0*c1,  c0*s1,  c0*c1}};
    float gx[4][4], gy[4][4];
    #pragma unroll
    for (int q = 0; q < 4; ++q){
      gx[0][q] = m[1][q];  gy[0][q] = 0.f;      // row swap from X(q1)
      gx[1][q] = m[0][q];  gy[1][q] = 0.f;
      gx[2][q] =  c3*c2*m[2][q] - s3*s2*m[3][q];
      gy[2][q] =  c3*s2*m[2][q] - s3*c2*m[3][q];
      gx[3][q] =  s3*s2*m[2][q] + c3*c2*m[3][q];
      gy[3][q] = -(s3*c2*m[2][q] + c3*s2*m[3][q]);
    }
    float* dst = coef + tid*32;
    #pragma unroll
    for (int r = 0; r < 4; ++r)
      #pragma unroll
      for (int q = 0; q < 4; ++q){
        dst[r*4+q]      = gx[r][q];
        dst[16+r*4+q]   = gy[r][q];
      }
  } else if (tid < 99){
    int r = tid - 72;
    int l = r / 9, i = r % 9;
    const float* w = weights + l*27 + 3*i;
    float phi = w[0], th = w[1], om = w[2];
    float sT,cT,sA,cA,sB,cB;
    __sincosf(0.5f*th, &sT, &cT);
    __sincosf(0.5f*(phi+om), &sA, &cA);
    __sincosf(0.5f*(om-phi), &sB, &cB);
    float* dst = coef + COEF_ROT_BASE + r*8;
    dst[0] =  cA*cT;  dst[1] = -sA*cT;   // u00
    dst[2] = -cB*sT;  dst[3] =  sB*sT;   // u01
    dst[4] =  cB*sT;  dst[5] =  sB*sT;   // u10
    dst[6] =  cA*cT;  dst[7] =  sA*cT;   // u11
  }
}

// =====================  2-wave register-resident statevector sim  =====================
// One block (2 waves, 128 thr) per column t. Amp index (9 bits):
//   bit 8 -> wave, bits 2-7 -> lane bits 0-5, bits 0-1 -> reg j.
// Wire w <-> bit (8-w).

template<int LM>
__device__ inline float lxor(float v){
  if constexpr (LM == 1)
    return __int_as_float(__builtin_amdgcn_mov_dpp(__float_as_int(v), 0xB1, 0xF, 0xF, true));
  else if constexpr (LM == 2)
    return __int_as_float(__builtin_amdgcn_mov_dpp(__float_as_int(v), 0x4E, 0xF, 0xF, true));
  else if constexpr (LM == 3)
    return __int_as_float(__builtin_amdgcn_mov_dpp(__float_as_int(v), 0x1B, 0xF, 0xF, true));
  else if constexpr (LM < 32)
    return __int_as_float(__builtin_amdgcn_ds_swizzle(__float_as_int(v), (LM<<10)|0x1F));
  else
    return __shfl_xor(v, LM);
}

// cross-wave exchange of all 4 complex amps
__device__ inline void wexch(float2* sh, int wv, int lane,
                             const float ax[4], const float ay[4],
                             float px[4], float py[4]){
  __syncthreads();
  #pragma unroll
  for (int j = 0; j < 4; ++j) sh[j*128 + (wv<<6) + lane] = make_float2(ax[j], ay[j]);
  __syncthreads();
  #pragma unroll
  for (int j = 0; j < 4; ++j){
    float2 p = sh[j*128 + ((wv^1)<<6) + lane];
    px[j] = p.x; py[j] = p.y;
  }
}

// h_d = G[p][p^d], p = (cb<<1)|tb, selected per lane
__device__ inline void hsel(const float* __restrict__ G, bool cb, bool tb,
                            float hx[4], float hy[4]){
  const float* Gx = G; const float* Gy = G + 16;
  #pragma unroll
  for (int d = 0; d < 4; ++d){
    float xa = tb ? Gx[4+(1^d)]  : Gx[d];
    float xb = tb ? Gx[12+(3^d)] : Gx[8+(2^d)];
    float ya = tb ? Gy[4+(1^d)]  : Gy[d];
    float yb = tb ? Gy[12+(3^d)] : Gy[8+(2^d)];
    hx[d] = cb ? xb : xa;
    hy[d] = cb ? yb : ya;
  }
}

__device__ inline void cfma(float& nx, float& ny, float hx, float hy, float vx, float vy){
  nx += hx*vx - hy*vy;
  ny += hx*vy + hy*vx;
}

// both wires in lane bits
template<int LC, int LT>
__device__ inline void step_ll(float ax[4], float ay[4], int lane, const float* __restrict__ G){
  float hx[4], hy[4];
  hsel(G, (lane & LC) != 0, (lane & LT) != 0, hx, hy);
  #pragma unroll
  for (int j = 0; j < 4; ++j){
    float ox = ax[j], oy = ay[j];
    float tx = lxor<LT>(ox),      ty = lxor<LT>(oy);
    float cx = lxor<LC>(ox),      cy = lxor<LC>(oy);
    float bx = lxor<(LC^LT)>(ox), by = lxor<(LC^LT)>(oy);
    float nx = 0.f, ny = 0.f;
    cfma(nx,ny,hx[0],hy[0],ox,oy);
    cfma(nx,ny,hx[1],hy[1],tx,ty);
    cfma(nx,ny,hx[2],hy[2],cx,cy);
    cfma(nx,ny,hx[3],hy[3],bx,by);
    ax[j] = nx; ay[j] = ny;
  }
}

// ctrl = wave bit, target = lane bit 5  (ent step I=0)
__device__ inline void step_wl(float ax[4], float ay[4], int lane, int wv,
                               float2* sh, const float* __restrict__ G){
  float pwx[4], pwy[4];
  wexch(sh, wv, lane, ax, ay, pwx, pwy);
  float hx[4], hy[4];
  hsel(G, wv != 0, (lane & 32) != 0, hx, hy);
  #pragma unroll
  for (int j = 0; j < 4; ++j){
    float ox = ax[j], oy = ay[j];
    float tx = lxor<32>(ox),     ty = lxor<32>(oy);
    float cx = pwx[j],           cy = pwy[j];
    float bx = lxor<32>(cx),     by = lxor<32>(cy);
    float nx = 0.f, ny = 0.f;
    cfma(nx,ny,hx[0],hy[0],ox,oy);
    cfma(nx,ny,hx[1],hy[1],tx,ty);
    cfma(nx,ny,hx[2],hy[2],cx,cy);
    cfma(nx,ny,hx[3],hy[3],bx,by);
    ax[j] = nx; ay[j] = ny;
  }
}

// ctrl = lane bit 0, target = reg bit 1  (ent step I=6)
__device__ inline void step_lr(float ax[4], float ay[4], int lane, const float* __restrict__ G){
  const float* Gx = G; const float* Gy = G + 16;
  bool cb = (lane & 1) != 0;
  float hx[2][4], hy[2][4];
  #pragma unroll
  for (int tb = 0; tb < 2; ++tb)
    #pragma unroll
    for (int d = 0; d < 4; ++d){
      int p0 = tb, p1 = 2|tb;
      hx[tb][d] = cb ? Gx[p1*4+(p1^d)] : Gx[p0*4+(p0^d)];
      hy[tb][d] = cb ? Gy[p1*4+(p1^d)] : Gy[p0*4+(p0^d)];
    }
  float nax[4], nay[4];
  #pragma unroll
  for (int j = 0; j < 4; ++j){
    int tb = (j>>1)&1, jt = j^2;
    float ox = ax[j],  oy = ay[j];
    float tx = ax[jt], ty = ay[jt];
    float cx = lxor<1>(ox), cy = lxor<1>(oy);
    float bx = lxor<1>(tx), by = lxor<1>(ty);
    float nx = 0.f, ny = 0.f;
    cfma(nx,ny,hx[tb][0],hy[tb][0],ox,oy);
    cfma(nx,ny,hx[tb][1],hy[tb][1],tx,ty);
    cfma(nx,ny,hx[tb][2],hy[tb][2],cx,cy);
    cfma(nx,ny,hx[tb][3],hy[tb][3],bx,by);
    nax[j] = nx; nay[j] = ny;
  }
  #pragma unroll
  for (int j = 0; j < 4; ++j){ ax[j] = nax[j]; ay[j] = nay[j]; }
}

// both wires in reg bits: ctrl bit1, target bit0  (ent step I=7); p == j
__device__ inline void step_rr(float ax[4], float ay[4], const float* __restrict__ G){
  const float* Gx = G; const float* Gy = G + 16;
  float nax[4], nay[4];
  #pragma unroll
  for (int p = 0; p < 4; ++p){
    float nx = 0.f, ny = 0.f;
    #pragma unroll
    for (int q = 0; q < 4; ++q)
      cfma(nx,ny,Gx[p*4+q],Gy[p*4+q],ax[q],ay[q]);
    nax[p] = nx; nay[p] = ny;
  }
  #pragma unroll
  for (int j = 0; j < 4; ++j){ ax[j] = nax[j]; ay[j] = nay[j]; }
}

// ctrl = reg bit 0, target = wave bit  (ent step I=8)
__device__ inline void step_rw(float ax[4], float ay[4], int lane, int wv,
                               float2* sh, const float* __restrict__ G){
  float pwx[4], pwy[4];
  wexch(sh, wv, lane, ax, ay, pwx, pwy);
  const float* Gx = G; const float* Gy = G + 16;
  bool tb = wv != 0;
  float hx[2][4], hy[2][4];
  #pragma unroll
  for (int cb = 0; cb < 2; ++cb)
    #pragma unroll
    for (int d = 0; d < 4; ++d){
      int p0 = cb<<1, p1 = (cb<<1)|1;
      hx[cb][d] = tb ? Gx[p1*4+(p1^d)] : Gx[p0*4+(p0^d)];
      hy[cb][d] = tb ? Gy[p1*4+(p1^d)] : Gy[p0*4+(p0^d)];
    }
  float nax[4], nay[4];
  #pragma unroll
  for (int j = 0; j < 4; ++j){
    int cb = j & 1;
    float ox = ax[j],   oy = ay[j];
    float tx = pwx[j],  ty = pwy[j];
    float cx = ax[j^1], cy = ay[j^1];
    float bx = pwx[j^1], by = pwy[j^1];
    float nx = 0.f, ny = 0.f;
    cfma(nx,ny,hx[cb][0],hy[cb][0],ox,oy);
    cfma(nx,ny,hx[cb][1],hy[cb][1],tx,ty);
    cfma(nx,ny,hx[cb][2],hy[cb][2],cx,cy);
    cfma(nx,ny,hx[cb][3],hy[cb][3],bx,by);
    nax[j] = nx; nay[j] = ny;
  }
  #pragma unroll
  for (int j = 0; j < 4; ++j){ ax[j] = nax[j]; ay[j] = nay[j]; }
}

// ---- Rot (1-qubit complex 2x2), coefs u[8] = u00,u01,u10,u11 (x,y pairs) ----
template<int LM>
__device__ inline void rot_l(float ax[4], float ay[4], int lane, const float* __restrict__ u){
  bool hi = (lane & LM) != 0;
  float cax = hi?u[6]:u[0], cay = hi?u[7]:u[1];
  float cbx = hi?u[4]:u[2], cby = hi?u[5]:u[3];
  #pragma unroll
  for (int j = 0; j < 4; ++j){
    float ox = ax[j], oy = ay[j];
    float px = lxor<LM>(ox), py = lxor<LM>(oy);
    ax[j] = cax*ox - cay*oy + cbx*px - cby*py;
    ay[j] = cax*oy + cay*ox + cbx*py + cby*px;
  }
}

template<int M>
__device__ inline void rot_r(float ax[4], float ay[4], const float* __restrict__ u){
  #pragma unroll
  for (int j0 = 0; j0 < 4; ++j0) if (!(j0 & M)){
    int j1 = j0 | M;
    float x0=ax[j0], y0=ay[j0], x1=ax[j1], y1=ay[j1];
    ax[j0] = u[0]*x0 - u[1]*y0 + u[2]*x1 - u[3]*y1;
    ay[j0] = u[0]*y0 + u[1]*x0 + u[2]*y1 + u[3]*x1;
    ax[j1] = u[4]*x0 - u[5]*y0 + u[6]*x1 - u[7]*y1;
    ay[j1] = u[4]*y0 + u[5]*x0 + u[6]*y1 + u[7]*x1;
  }
}

__device__ inline void rot_w(float ax[4], float ay[4], int lane, int wv, float2* sh,
                             const float* __restrict__ u){
  float pwx[4], pwy[4];
  wexch(sh, wv, lane, ax, ay, pwx, pwy);
  bool hi = wv != 0;
  float cax = hi?u[6]:u[0], cay = hi?u[7]:u[1];
  float cbx = hi?u[4]:u[2], cby = hi?u[5]:u[3];
  #pragma unroll
  for (int j = 0; j < 4; ++j){
    float ox = ax[j], oy = ay[j], px = pwx[j], py = pwy[j];
    ax[j] = cax*ox - cay*oy + cbx*px - cby*py;
    ay[j] = cax*oy + cay*ox + cbx*py + cby*px;
  }
}

// CNOT ring of range R: one LDS permutation round-trip.
template<int R>
__device__ inline void ring(float ax[4], float ay[4], int lane, int wv, float2* sh){
  __syncthreads();
  int base = (wv<<8) | (lane<<2);
  #pragma unroll
  for (int j = 0; j < 4; ++j) sh[base+j] = make_float2(ax[j], ay[j]);
  __syncthreads();
  #pragma unroll
  for (int j = 0; j < 4; ++j){
    int s = base + j;
    #pragma unroll
    for (int i = 8; i >= 0; --i){
      int bc = 8 - i, bt = 8 - ((i + R) % 9);
      s ^= ((s >> bc) & 1) << bt;
    }
    float2 v = sh[s];
    ax[j] = v.x; ay[j] = v.y;
  }
}

// ---------------- compile-time drivers (coef from LDS) ----------------

template<int BLK, int I = 0>
__device__ inline void ent_block(float ax[4], float ay[4], int lane, int wv, float2* sh,
                                 const float* scoef){
  const float* G = scoef + (BLK*9 + I)*32;
  if constexpr      (I == 0) step_wl(ax, ay, lane, wv, sh, G);
  else if constexpr (I == 1) step_ll<32,16>(ax, ay, lane, G);
  else if constexpr (I == 2) step_ll<16, 8>(ax, ay, lane, G);
  else if constexpr (I == 3) step_ll< 8, 4>(ax, ay, lane, G);
  else if constexpr (I == 4) step_ll< 4, 2>(ax, ay, lane, G);
  else if constexpr (I == 5) step_ll< 2, 1>(ax, ay, lane, G);
  else if constexpr (I == 6) step_lr(ax, ay, lane, G);
  else if constexpr (I == 7) step_rr(ax, ay, G);
  else                       step_rw(ax, ay, lane, wv, sh, G);
  if constexpr (I < 8) ent_block<BLK, I+1>(ax, ay, lane, wv, sh, scoef);
}

template<int L, int I = 0>
__device__ inline void sel_rots(float ax[4], float ay[4], int lane, int wv, float2* sh,
                                const float* scoef){
  const float* u = scoef + COEF_ROT_BASE + (L*9 + I)*8;
  if constexpr      (I == 0) rot_w(ax, ay, lane, wv, sh, u);
  else if constexpr (I == 1) rot_l<32>(ax, ay, lane, u);
  else if constexpr (I == 2) rot_l<16>(ax, ay, lane, u);
  else if constexpr (I == 3) rot_l< 8>(ax, ay, lane, u);
  else if constexpr (I == 4) rot_l< 4>(ax, ay, lane, u);
  else if constexpr (I == 5) rot_l< 2>(ax, ay, lane, u);
  else if constexpr (I == 6) rot_l< 1>(ax, ay, lane, u);
  else if constexpr (I == 7) rot_r< 2>(ax, ay, u);
  else                       rot_r< 1>(ax, ay, u);
  if constexpr (I < 8) sel_rots<L, I+1>(ax, ay, lane, wv, sh, scoef);
}

__global__ __launch_bounds__(128) void sim_V(const float* __restrict__ coef,
                                             unsigned short* __restrict__ A2){
  __shared__ float2 sh[512];
  __shared__ float scoef[COEF_PAD];
  int tid = threadIdx.x;
  // stage all coefficients into LDS (coalesced float4 loads)
  #pragma unroll
  for (int k = 0; k < COEF_PAD/4/128; ++k)
    *(float4*)(scoef + (k*128 + tid)*4) = *(const float4*)(coef + (k*128 + tid)*4);
  __syncthreads();

  int t = blockIdx.x;
  int wv = tid >> 6, lane = tid & 63;
  float ax[4], ay[4];
  int pc = __popc((unsigned)t) & 3;
  float prx = (pc==0) ? 1.f : (pc==2 ? -1.f : 0.f);
  float pry = (pc==3) ? 1.f : (pc==1 ? -1.f : 0.f);
  int wv_t = t >> 8, ln_t = (t >> 2) & 63, j_t = t & 3;
  #pragma unroll
  for (int j = 0; j < 4; ++j){
    bool hit = (wv == wv_t) && (lane == ln_t) && (j == j_t);
    ax[j] = hit ? prx : 0.f;
    ay[j] = hit ? pry : 0.f;
  }
  ent_block<0>(ax, ay, lane, wv, sh, scoef);
  ent_block<1>(ax, ay, lane, wv, sh, scoef);
  ent_block<2>(ax, ay, lane, wv, sh, scoef);
  sel_rots<0>(ax, ay, lane, wv, sh, scoef);  ring<1>(ax, ay, lane, wv, sh);
  sel_rots<1>(ax, ay, lane, wv, sh, scoef);  ring<2>(ax, ay, lane, wv, sh);
  sel_rots<2>(ax, ay, lane, wv, sh, scoef);  ring<3>(ax, ay, lane, wv, sh);
  ent_block<3>(ax, ay, lane, wv, sh, scoef);
  ent_block<4>(ax, ay, lane, wv, sh, scoef);
  ent_block<5>(ax, ay, lane, wv, sh, scoef);
  ent_block<6>(ax, ay, lane, wv, sh, scoef);
  ent_block<7>(ax, ay, lane, wv, sh, scoef);

  int sbase = (wv << 8) | (lane << 2);
  #pragma unroll
  for (int j = 0; j < 4; ++j){
    int s = sbase + j;
    A2[(size_t)s * NS + t]        = f2bf(ax[j]);
    A2[(size_t)(s + NS) * NS + t] = f2bf(ay[j]);
  }
}

// build_c (wave per sample, coalesced 16B stores) + zero the output accumulator
__global__ __launch_bounds__(256) void prep(const float* __restrict__ adds,
                                            unsigned short* __restrict__ cT,
                                            float* __restrict__ out, int B){
  int gid = blockIdx.x * 256 + threadIdx.x;
  int b = gid >> 6;
  int lane = gid & 63;
  if (b < B){
    const float* ab = adds + b * NQ;
    float cw[NQ], sw[NQ];
    #pragma unroll
    for (int w = 0; w < NQ; ++w)
      __sincosf(0.5f * ab[w], &sw[w], &cw[w]);
    float p6 = 1.f;
    #pragma unroll
    for (int w = 0; w < 6; ++w)
      p6 *= ((lane >> (5 - w)) & 1) ? sw[w] : cw[w];
    union { unsigned short u[8]; uint4 v; } pk;
    #pragma unroll
    for (int j = 0; j < 8; ++j){
      float p = p6 * (((j>>2)&1) ? sw[6] : cw[6])
                   * (((j>>1)&1) ? sw[7] : cw[7])
                   * (( j    &1) ? sw[8] : cw[8]);
      pk.u[j] = f2bf(p);
    }
    *(uint4*)(cT + (size_t)b * NS + lane*8) = pk.v;
  }
  if (gid < B) out[gid] = 0.f;
}

// Phi2 = A2(1024x512) @ c(512xB); out[b] = sum_row sign(row) * Phi2[row][b]^2,
// sign(row) = -1 iff (row & 256).
__global__ __launch_bounds__(256) void gemm_out(const unsigned short* __restrict__ A2,
                                                const unsigned short* __restrict__ cT,
                                                float* __restrict__ out){
  int bx = blockIdx.x;            // N tile (128 cols of b)
  int by = blockIdx.y;            // M tile (128 rows), 8 tiles
  int tid = threadIdx.x;
  int wave = tid >> 6, lane = tid & 63;
  int wy = wave >> 1, wx = wave & 1;
  int lane15 = lane & 15, quad = lane >> 4;
  int rowBase = by*128 + wy*64;
  int colBase = bx*128 + wx*64;
  const short* Ap = (const short*)A2;   // [row][k]
  const short* Bp = (const short*)cT;   // [col][k]

  f32x4 acc[4][4];
  #pragma unroll
  for (int i = 0; i < 4; ++i)
    #pragma unroll
    for (int j = 0; j < 4; ++j)
      acc[i][j] = (f32x4){0.f, 0.f, 0.f, 0.f};

  #pragma unroll 2
  for (int k0 = 0; k0 < NS; k0 += 32){
    bf16x8 a[4], b[4];
    #pragma unroll
    for (int mi = 0; mi < 4; ++mi)
      a[mi] = *(const bf16x8*)(Ap + (size_t)(rowBase + mi*16 + lane15)*NS + k0 + quad*8);
    #pragma unroll
    for (int ni = 0; ni < 4; ++ni)
      b[ni] = *(const bf16x8*)(Bp + (size_t)(colBase + ni*16 + lane15)*NS + k0 + quad*8);
    #pragma unroll
    for (int mi = 0; mi < 4; ++mi)
      #pragma unroll
      for (int ni = 0; ni < 4; ++ni)
        acc[mi][ni] = __builtin_amdgcn_mfma_f32_16x16x32_bf16(a[mi], b[ni], acc[mi][ni], 0, 0, 0);
  }

  float sign = (by & 2) ? -1.f : 1.f;
  #pragma unroll
  for (int ni = 0; ni < 4; ++ni){
    float cs = 0.f;
    #pragma unroll
    for (int mi = 0; mi < 4; ++mi)
      #pragma unroll
      for (int r = 0; r < 4; ++r)
        cs += acc[mi][ni][r] * acc[mi][ni][r];
    cs += __shfl_xor(cs, 16);
    cs += __shfl_xor(cs, 32);
    if (quad == 0)
      atomicAdd(out + colBase + ni*16 + lane15, sign * cs);
  }
}

extern "C" void kernel_launch(void* const* d_in, const int* in_sizes, int n_in,
                              void* d_out, int out_size, void* d_ws, size_t ws_size,
                              hipStream_t stream) {
  const float* adds    = (const float*)d_in[0];
  const float* params  = (const float*)d_in[1];
  const float* weights = (const float*)d_in[2];
  const float* params2 = (const float*)d_in[3];
  float* out = (float*)d_out;
  int B = in_sizes[0] / NQ;   // 8192

  unsigned short* A2 = (unsigned short*)d_ws;        // 1024*512 bf16 = 1 MB
  unsigned short* cT = A2 + (size_t)M2 * NS;         // B*512 bf16 = 8 MB
  size_t base = (size_t)M2*NS*2 + (size_t)B*NS*2;    // 9 MB
  float* coef = (ws_size >= base + COEF_PAD*sizeof(float))
              ? (float*)((char*)d_ws + base)
              : (float*)d_out;

  hipLaunchKernelGGL(precoef, dim3(1), dim3(128), 0, stream, params, weights, params2, coef);
  hipLaunchKernelGGL(sim_V, dim3(NS), dim3(128), 0, stream, coef, A2);
  hipLaunchKernelGGL(prep, dim3((B * 64 + 255) / 256), dim3(256), 0, stream, adds, cT, out, B);
  hipLaunchKernelGGL(gemm_out, dim3(B / 128, 8), dim3(256), 0, stream, A2, cT, out);
}

// Round 6
// 140.121 us; speedup vs baseline: 1.0772x; 1.0086x over previous
//
#include <hip/hip_runtime.h>

#define NQ 9
#define NS 512            // 2^9 amplitudes
#define M2 1024           // [Re V; Im V] stacked rows

#define COEF_ROT_BASE (72*32)                 // 72 ent steps x 32 floats
#define COEF_FLOATS   (COEF_ROT_BASE + 27*8)  // + 27 rots x 8 floats = 2520

typedef __attribute__((ext_vector_type(8))) short bf16x8;
typedef __attribute__((ext_vector_type(4))) float f32x4;

__device__ inline unsigned short f2bf(float f){
  unsigned int u = __float_as_uint(f);
  u += 0x7fffu + ((u >> 16) & 1u);   // round-to-nearest-even
  return (unsigned short)(u >> 16);
}

// =====================  2-wave register-resident statevector sim  =====================
// One block (2 waves, 128 thr) per column t. Amp index (9 bits):
//   bit 8 -> wave, bits 2-7 -> lane bits 0-5, bits 0-1 -> reg j.
// Wire w <-> bit (8-w).

template<int LM>
__device__ inline float lxor(float v){
  if constexpr (LM == 1)
    return __int_as_float(__builtin_amdgcn_mov_dpp(__float_as_int(v), 0xB1, 0xF, 0xF, true));
  else if constexpr (LM == 2)
    return __int_as_float(__builtin_amdgcn_mov_dpp(__float_as_int(v), 0x4E, 0xF, 0xF, true));
  else if constexpr (LM == 3)
    return __int_as_float(__builtin_amdgcn_mov_dpp(__float_as_int(v), 0x1B, 0xF, 0xF, true));
  else if constexpr (LM < 32)
    return __int_as_float(__builtin_amdgcn_ds_swizzle(__float_as_int(v), (LM<<10)|0x1F));
  else
    return __shfl_xor(v, LM);
}

// cross-wave exchange of all 4 complex amps
__device__ inline void wexch(float2* sh, int wv, int lane,
                             const float ax[4], const float ay[4],
                             float px[4], float py[4]){
  __syncthreads();
  #pragma unroll
  for (int j = 0; j < 4; ++j) sh[j*128 + (wv<<6) + lane] = make_float2(ax[j], ay[j]);
  __syncthreads();
  #pragma unroll
  for (int j = 0; j < 4; ++j){
    float2 p = sh[j*128 + ((wv^1)<<6) + lane];
    px[j] = p.x; py[j] = p.y;
  }
}

// h_d = G[p][p^d], p = (cb<<1)|tb, selected per lane
__device__ inline void hsel(const float* G, bool cb, bool tb,
                            float hx[4], float hy[4]){
  const float* Gx = G; const float* Gy = G + 16;
  #pragma unroll
  for (int d = 0; d < 4; ++d){
    float xa = tb ? Gx[4+(1^d)]  : Gx[d];
    float xb = tb ? Gx[12+(3^d)] : Gx[8+(2^d)];
    float ya = tb ? Gy[4+(1^d)]  : Gy[d];
    float yb = tb ? Gy[12+(3^d)] : Gy[8+(2^d)];
    hx[d] = cb ? xb : xa;
    hy[d] = cb ? yb : ya;
  }
}

__device__ inline void cfma(float& nx, float& ny, float hx, float hy, float vx, float vy){
  nx += hx*vx - hy*vy;
  ny += hx*vy + hy*vx;
}

// both wires in lane bits
template<int LC, int LT>
__device__ inline void step_ll(float ax[4], float ay[4], int lane, const float* G){
  float hx[4], hy[4];
  hsel(G, (lane & LC) != 0, (lane & LT) != 0, hx, hy);
  #pragma unroll
  for (int j = 0; j < 4; ++j){
    float ox = ax[j], oy = ay[j];
    float tx = lxor<LT>(ox),      ty = lxor<LT>(oy);
    float cx = lxor<LC>(ox),      cy = lxor<LC>(oy);
    float bx = lxor<(LC^LT)>(ox), by = lxor<(LC^LT)>(oy);
    float nx = 0.f, ny = 0.f;
    cfma(nx,ny,hx[0],hy[0],ox,oy);
    cfma(nx,ny,hx[1],hy[1],tx,ty);
    cfma(nx,ny,hx[2],hy[2],cx,cy);
    cfma(nx,ny,hx[3],hy[3],bx,by);
    ax[j] = nx; ay[j] = ny;
  }
}

// ctrl = wave bit, target = lane bit 5  (ent step I=0)
__device__ inline void step_wl(float ax[4], float ay[4], int lane, int wv,
                               float2* sh, const float* G){
  float pwx[4], pwy[4];
  wexch(sh, wv, lane, ax, ay, pwx, pwy);
  float hx[4], hy[4];
  hsel(G, wv != 0, (lane & 32) != 0, hx, hy);
  #pragma unroll
  for (int j = 0; j < 4; ++j){
    float ox = ax[j], oy = ay[j];
    float tx = lxor<32>(ox),     ty = lxor<32>(oy);
    float cx = pwx[j],           cy = pwy[j];
    float bx = lxor<32>(cx),     by = lxor<32>(cy);
    float nx = 0.f, ny = 0.f;
    cfma(nx,ny,hx[0],hy[0],ox,oy);
    cfma(nx,ny,hx[1],hy[1],tx,ty);
    cfma(nx,ny,hx[2],hy[2],cx,cy);
    cfma(nx,ny,hx[3],hy[3],bx,by);
    ax[j] = nx; ay[j] = ny;
  }
}

// ctrl = lane bit 0, target = reg bit 1  (ent step I=6)
__device__ inline void step_lr(float ax[4], float ay[4], int lane, const float* G){
  const float* Gx = G; const float* Gy = G + 16;
  bool cb = (lane & 1) != 0;
  float hx[2][4], hy[2][4];
  #pragma unroll
  for (int tb = 0; tb < 2; ++tb)
    #pragma unroll
    for (int d = 0; d < 4; ++d){
      int p0 = tb, p1 = 2|tb;
      hx[tb][d] = cb ? Gx[p1*4+(p1^d)] : Gx[p0*4+(p0^d)];
      hy[tb][d] = cb ? Gy[p1*4+(p1^d)] : Gy[p0*4+(p0^d)];
    }
  float nax[4], nay[4];
  #pragma unroll
  for (int j = 0; j < 4; ++j){
    int tb = (j>>1)&1, jt = j^2;
    float ox = ax[j],  oy = ay[j];
    float tx = ax[jt], ty = ay[jt];
    float cx = lxor<1>(ox), cy = lxor<1>(oy);
    float bx = lxor<1>(tx), by = lxor<1>(ty);
    float nx = 0.f, ny = 0.f;
    cfma(nx,ny,hx[tb][0],hy[tb][0],ox,oy);
    cfma(nx,ny,hx[tb][1],hy[tb][1],tx,ty);
    cfma(nx,ny,hx[tb][2],hy[tb][2],cx,cy);
    cfma(nx,ny,hx[tb][3],hy[tb][3],bx,by);
    nax[j] = nx; nay[j] = ny;
  }
  #pragma unroll
  for (int j = 0; j < 4; ++j){ ax[j] = nax[j]; ay[j] = nay[j]; }
}

// both wires in reg bits: ctrl bit1, target bit0  (ent step I=7); p == j
__device__ inline void step_rr(float ax[4], float ay[4], const float* G){
  const float* Gx = G; const float* Gy = G + 16;
  float nax[4], nay[4];
  #pragma unroll
  for (int p = 0; p < 4; ++p){
    float nx = 0.f, ny = 0.f;
    #pragma unroll
    for (int q = 0; q < 4; ++q)
      cfma(nx,ny,Gx[p*4+q],Gy[p*4+q],ax[q],ay[q]);
    nax[p] = nx; nay[p] = ny;
  }
  #pragma unroll
  for (int j = 0; j < 4; ++j){ ax[j] = nax[j]; ay[j] = nay[j]; }
}

// ctrl = reg bit 0, target = wave bit  (ent step I=8)
__device__ inline void step_rw(float ax[4], float ay[4], int lane, int wv,
                               float2* sh, const float* G){
  float pwx[4], pwy[4];
  wexch(sh, wv, lane, ax, ay, pwx, pwy);
  const float* Gx = G; const float* Gy = G + 16;
  bool tb = wv != 0;
  float hx[2][4], hy[2][4];
  #pragma unroll
  for (int cb = 0; cb < 2; ++cb)
    #pragma unroll
    for (int d = 0; d < 4; ++d){
      int p0 = cb<<1, p1 = (cb<<1)|1;
      hx[cb][d] = tb ? Gx[p1*4+(p1^d)] : Gx[p0*4+(p0^d)];
      hy[cb][d] = tb ? Gy[p1*4+(p1^d)] : Gy[p0*4+(p0^d)];
    }
  float nax[4], nay[4];
  #pragma unroll
  for (int j = 0; j < 4; ++j){
    int cb = j & 1;
    float ox = ax[j],   oy = ay[j];
    float tx = pwx[j],  ty = pwy[j];
    float cx = ax[j^1], cy = ay[j^1];
    float bx = pwx[j^1], by = pwy[j^1];
    float nx = 0.f, ny = 0.f;
    cfma(nx,ny,hx[cb][0],hy[cb][0],ox,oy);
    cfma(nx,ny,hx[cb][1],hy[cb][1],tx,ty);
    cfma(nx,ny,hx[cb][2],hy[cb][2],cx,cy);
    cfma(nx,ny,hx[cb][3],hy[cb][3],bx,by);
    nax[j] = nx; nay[j] = ny;
  }
  #pragma unroll
  for (int j = 0; j < 4; ++j){ ax[j] = nax[j]; ay[j] = nay[j]; }
}

// ---- Rot (1-qubit complex 2x2), coefs u[8] = u00,u01,u10,u11 (x,y pairs) ----
template<int LM>
__device__ inline void rot_l(float ax[4], float ay[4], int lane, const float* u){
  bool hi = (lane & LM) != 0;
  float cax = hi?u[6]:u[0], cay = hi?u[7]:u[1];
  float cbx = hi?u[4]:u[2], cby = hi?u[5]:u[3];
  #pragma unroll
  for (int j = 0; j < 4; ++j){
    float ox = ax[j], oy = ay[j];
    float px = lxor<LM>(ox), py = lxor<LM>(oy);
    ax[j] = cax*ox - cay*oy + cbx*px - cby*py;
    ay[j] = cax*oy + cay*ox + cbx*py + cby*px;
  }
}

template<int M>
__device__ inline void rot_r(float ax[4], float ay[4], const float* u){
  #pragma unroll
  for (int j0 = 0; j0 < 4; ++j0) if (!(j0 & M)){
    int j1 = j0 | M;
    float x0=ax[j0], y0=ay[j0], x1=ax[j1], y1=ay[j1];
    ax[j0] = u[0]*x0 - u[1]*y0 + u[2]*x1 - u[3]*y1;
    ay[j0] = u[0]*y0 + u[1]*x0 + u[2]*y1 + u[3]*x1;
    ax[j1] = u[4]*x0 - u[5]*y0 + u[6]*x1 - u[7]*y1;
    ay[j1] = u[4]*y0 + u[5]*x0 + u[6]*y1 + u[7]*x1;
  }
}

__device__ inline void rot_w(float ax[4], float ay[4], int lane, int wv, float2* sh,
                             const float* u){
  float pwx[4], pwy[4];
  wexch(sh, wv, lane, ax, ay, pwx, pwy);
  bool hi = wv != 0;
  float cax = hi?u[6]:u[0], cay = hi?u[7]:u[1];
  float cbx = hi?u[4]:u[2], cby = hi?u[5]:u[3];
  #pragma unroll
  for (int j = 0; j < 4; ++j){
    float ox = ax[j], oy = ay[j], px = pwx[j], py = pwy[j];
    ax[j] = cax*ox - cay*oy + cbx*px - cby*py;
    ay[j] = cax*oy + cay*ox + cbx*py + cby*px;
  }
}

// CNOT ring of range R (runtime): one LDS permutation round-trip.
__device__ inline void ring_rt(float ax[4], float ay[4], int lane, int wv, float2* sh, int R){
  __syncthreads();
  int base = (wv<<8) | (lane<<2);
  #pragma unroll
  for (int j = 0; j < 4; ++j) sh[base+j] = make_float2(ax[j], ay[j]);
  __syncthreads();
  #pragma unroll
  for (int j = 0; j < 4; ++j){
    int s = base + j;
    for (int i = 8; i >= 0; --i){
      int bc = 8 - i;
      int it = i + R; if (it >= 9) it -= 9;
      int bt = 8 - it;
      s ^= ((s >> bc) & 1) << bt;
    }
    float2 v = sh[s];
    ax[j] = v.x; ay[j] = v.y;
  }
}

// ---------------- loopable drivers (runtime coef base, I unrolled) ----------------

template<int I = 0>
__device__ inline void ent_blk(float ax[4], float ay[4], int lane, int wv, float2* sh,
                               const float* Gbase){
  const float* G = Gbase + I*32;
  if constexpr      (I == 0) step_wl(ax, ay, lane, wv, sh, G);
  else if constexpr (I == 1) step_ll<32,16>(ax, ay, lane, G);
  else if constexpr (I == 2) step_ll<16, 8>(ax, ay, lane, G);
  else if constexpr (I == 3) step_ll< 8, 4>(ax, ay, lane, G);
  else if constexpr (I == 4) step_ll< 4, 2>(ax, ay, lane, G);
  else if constexpr (I == 5) step_ll< 2, 1>(ax, ay, lane, G);
  else if constexpr (I == 6) step_lr(ax, ay, lane, G);
  else if constexpr (I == 7) step_rr(ax, ay, G);
  else                       step_rw(ax, ay, lane, wv, sh, G);
  if constexpr (I < 8) ent_blk<I+1>(ax, ay, lane, wv, sh, Gbase);
}

template<int I = 0>
__device__ inline void sel_rots_rt(float ax[4], float ay[4], int lane, int wv, float2* sh,
                                   const float* ubase){
  const float* u = ubase + I*8;
  if constexpr      (I == 0) rot_w(ax, ay, lane, wv, sh, u);
  else if constexpr (I == 1) rot_l<32>(ax, ay, lane, u);
  else if constexpr (I == 2) rot_l<16>(ax, ay, lane, u);
  else if constexpr (I == 3) rot_l< 8>(ax, ay, lane, u);
  else if constexpr (I == 4) rot_l< 4>(ax, ay, lane, u);
  else if constexpr (I == 5) rot_l< 2>(ax, ay, lane, u);
  else if constexpr (I == 6) rot_l< 1>(ax, ay, lane, u);
  else if constexpr (I == 7) rot_r< 2>(ax, ay, u);
  else                       rot_r< 1>(ax, ay, u);
  if constexpr (I < 8) sel_rots_rt<I+1>(ax, ay, lane, wv, sh, ubase);
}

__global__ __launch_bounds__(128) void sim_V(const float* __restrict__ params,
                                             const float* __restrict__ weights,
                                             const float* __restrict__ params2,
                                             unsigned short* __restrict__ A2){
  __shared__ float2 sh[512];
  __shared__ float scoef[COEF_FLOATS];
  int tid = threadIdx.x;

  // ---- inline coefficient precompute (each block builds its own LDS table) ----
  if (tid < 72){
    int blk = tid / 9, I = tid % 9;
    const float* p = (blk < 3) ? params + blk*36 : params2 + (blk-3)*36;
    float s0,c0,s1,c1,s2,c2,s3,c3;
    __sincosf(0.5f*p[4*I+0], &s0, &c0);
    __sincosf(0.5f*p[4*I+1], &s1, &c1);
    __sincosf(0.5f*p[4*I+2], &s2, &c2);
    __sincosf(0.5f*p[4*I+3], &s3, &c3);
    float m[4][4] = {
      { c0*c1, -c0*s1, -s0*c1,  s0*s1},
      { c0*s1,  c0*c1, -s0*s1, -s0*c1},
      { s0*c1, -s0*s1,  c0*c1, -c0*s1},
      { s0*s1,  s0*c1,  c0*s1,  c0*c1}};
    float* dst = scoef + tid*32;
    #pragma unroll
    for (int q = 0; q < 4; ++q){
      dst[0*4+q]    = m[1][q];  dst[16+0*4+q] = 0.f;
      dst[1*4+q]    = m[0][q];  dst[16+1*4+q] = 0.f;
      dst[2*4+q]    =  c3*c2*m[2][q] - s3*s2*m[3][q];
      dst[16+2*4+q] =  c3*s2*m[2][q] - s3*c2*m[3][q];
      dst[3*4+q]    =  s3*s2*m[2][q] + c3*c2*m[3][q];
      dst[16+3*4+q] = -(s3*c2*m[2][q] + c3*s2*m[3][q]);
    }
  } else if (tid < 99){
    int r = tid - 72;
    int l = r / 9, i = r % 9;
    const float* w = weights + l*27 + 3*i;
    float phi = w[0], th = w[1], om = w[2];
    float sT,cT,sA,cA,sB,cB;
    __sincosf(0.5f*th, &sT, &cT);
    __sincosf(0.5f*(phi+om), &sA, &cA);
    __sincosf(0.5f*(om-phi), &sB, &cB);
    float* dst = scoef + COEF_ROT_BASE + r*8;
    dst[0] =  cA*cT;  dst[1] = -sA*cT;
    dst[2] = -cB*sT;  dst[3] =  sB*sT;
    dst[4] =  cB*sT;  dst[5] =  sB*sT;
    dst[6] =  cA*cT;  dst[7] =  sA*cT;
  }
  __syncthreads();

  int t = blockIdx.x;
  int wv = tid >> 6, lane = tid & 63;
  float ax[4], ay[4];
  int pc = __popc((unsigned)t) & 3;
  float prx = (pc==0) ? 1.f : (pc==2 ? -1.f : 0.f);
  float pry = (pc==3) ? 1.f : (pc==1 ? -1.f : 0.f);
  int wv_t = t >> 8, ln_t = (t >> 2) & 63, j_t = t & 3;
  #pragma unroll
  for (int j = 0; j < 4; ++j){
    bool hit = (wv == wv_t) && (lane == ln_t) && (j == j_t);
    ax[j] = hit ? prx : 0.f;
    ay[j] = hit ? pry : 0.f;
  }

  #pragma unroll 1
  for (int blk = 0; blk < 3; ++blk)
    ent_blk<0>(ax, ay, lane, wv, sh, scoef + blk*288);
  #pragma unroll 1
  for (int L = 0; L < 3; ++L){
    sel_rots_rt<0>(ax, ay, lane, wv, sh, scoef + COEF_ROT_BASE + L*72);
    ring_rt(ax, ay, lane, wv, sh, L + 1);
  }
  #pragma unroll 1
  for (int blk = 3; blk < 8; ++blk)
    ent_blk<0>(ax, ay, lane, wv, sh, scoef + blk*288);

  int sbase = (wv << 8) | (lane << 2);
  #pragma unroll
  for (int j = 0; j < 4; ++j){
    int s = sbase + j;
    A2[(size_t)s * NS + t]        = f2bf(ax[j]);
    A2[(size_t)(s + NS) * NS + t] = f2bf(ay[j]);
  }
}

// build_c (wave per sample, coalesced 16B stores) + zero the output accumulator
__global__ __launch_bounds__(256) void prep(const float* __restrict__ adds,
                                            unsigned short* __restrict__ cT,
                                            float* __restrict__ out, int B){
  int gid = blockIdx.x * 256 + threadIdx.x;
  int b = gid >> 6;
  int lane = gid & 63;
  if (b < B){
    const float* ab = adds + b * NQ;
    float cw[NQ], sw[NQ];
    #pragma unroll
    for (int w = 0; w < NQ; ++w)
      __sincosf(0.5f * ab[w], &sw[w], &cw[w]);
    float p6 = 1.f;
    #pragma unroll
    for (int w = 0; w < 6; ++w)
      p6 *= ((lane >> (5 - w)) & 1) ? sw[w] : cw[w];
    union { unsigned short u[8]; uint4 v; } pk;
    #pragma unroll
    for (int j = 0; j < 8; ++j){
      float p = p6 * (((j>>2)&1) ? sw[6] : cw[6])
                   * (((j>>1)&1) ? sw[7] : cw[7])
                   * (( j    &1) ? sw[8] : cw[8]);
      pk.u[j] = f2bf(p);
    }
    *(uint4*)(cT + (size_t)b * NS + lane*8) = pk.v;
  }
  if (gid < B) out[gid] = 0.f;
}

// Phi2 = A2(1024x512) @ c(512xB); out[b] = sum_row sign(row) * Phi2[row][b]^2,
// sign(row) = -1 iff (row & 256).
__global__ __launch_bounds__(256) void gemm_out(const unsigned short* __restrict__ A2,
                                                const unsigned short* __restrict__ cT,
                                                float* __restrict__ out){
  int bx = blockIdx.x;            // N tile (128 cols of b)
  int by = blockIdx.y;            // M tile (128 rows), 8 tiles
  int tid = threadIdx.x;
  int wave = tid >> 6, lane = tid & 63;
  int wy = wave >> 1, wx = wave & 1;
  int lane15 = lane & 15, quad = lane >> 4;
  int rowBase = by*128 + wy*64;
  int colBase = bx*128 + wx*64;
  const short* Ap = (const short*)A2;   // [row][k]
  const short* Bp = (const short*)cT;   // [col][k]

  f32x4 acc[4][4];
  #pragma unroll
  for (int i = 0; i < 4; ++i)
    #pragma unroll
    for (int j = 0; j < 4; ++j)
      acc[i][j] = (f32x4){0.f, 0.f, 0.f, 0.f};

  #pragma unroll 2
  for (int k0 = 0; k0 < NS; k0 += 32){
    bf16x8 a[4], b[4];
    #pragma unroll
    for (int mi = 0; mi < 4; ++mi)
      a[mi] = *(const bf16x8*)(Ap + (size_t)(rowBase + mi*16 + lane15)*NS + k0 + quad*8);
    #pragma unroll
    for (int ni = 0; ni < 4; ++ni)
      b[ni] = *(const bf16x8*)(Bp + (size_t)(colBase + ni*16 + lane15)*NS + k0 + quad*8);
    #pragma unroll
    for (int mi = 0; mi < 4; ++mi)
      #pragma unroll
      for (int ni = 0; ni < 4; ++ni)
        acc[mi][ni] = __builtin_amdgcn_mfma_f32_16x16x32_bf16(a[mi], b[ni], acc[mi][ni], 0, 0, 0);
  }

  float sign = (by & 2) ? -1.f : 1.f;
  #pragma unroll
  for (int ni = 0; ni < 4; ++ni){
    float cs = 0.f;
    #pragma unroll
    for (int mi = 0; mi < 4; ++mi)
      #pragma unroll
      for (int r = 0; r < 4; ++r)
        cs += acc[mi][ni][r] * acc[mi][ni][r];
    cs += __shfl_xor(cs, 16);
    cs += __shfl_xor(cs, 32);
    if (quad == 0)
      atomicAdd(out + colBase + ni*16 + lane15, sign * cs);
  }
}

extern "C" void kernel_launch(void* const* d_in, const int* in_sizes, int n_in,
                              void* d_out, int out_size, void* d_ws, size_t ws_size,
                              hipStream_t stream) {
  const float* adds    = (const float*)d_in[0];
  const float* params  = (const float*)d_in[1];
  const float* weights = (const float*)d_in[2];
  const float* params2 = (const float*)d_in[3];
  float* out = (float*)d_out;
  int B = in_sizes[0] / NQ;   // 8192

  unsigned short* A2 = (unsigned short*)d_ws;        // 1024*512 bf16 = 1 MB
  unsigned short* cT = A2 + (size_t)M2 * NS;         // B*512 bf16 = 8 MB

  hipLaunchKernelGGL(sim_V, dim3(NS), dim3(128), 0, stream, params, weights, params2, A2);
  hipLaunchKernelGGL(prep, dim3((B * 64 + 255) / 256), dim3(256), 0, stream, adds, cT, out, B);
  hipLaunchKernelGGL(gemm_out, dim3(B / 128, 8), dim3(256), 0, stream, A2, cT, out);
}

// Round 7
// 126.371 us; speedup vs baseline: 1.1944x; 1.1088x over previous
//
#include <hip/hip_runtime.h>

#define NQ 9
#define NS 512            // 2^9 amplitudes
#define M2 1024           // [Re V; Im V] stacked rows

#define COEF_ROT_BASE (72*32)                 // 72 ent steps x 32 floats
#define COEF_FLOATS   (COEF_ROT_BASE + 27*8)  // + 27 rots x 8 floats = 2520

typedef __attribute__((ext_vector_type(8))) short bf16x8;
typedef __attribute__((ext_vector_type(4))) float f32x4;

__device__ inline unsigned short f2bf(float f){
  unsigned int u = __float_as_uint(f);
  u += 0x7fffu + ((u >> 16) & 1u);   // round-to-nearest-even
  return (unsigned short)(u >> 16);
}

// =====================  4-wave register-resident statevector sim  =====================
// One block (4 waves, 256 thr) per column t. Amp index i (9 bits):
//   bit 8 -> wv bit1, bit 7 -> wv bit0, bits 1-6 -> lane bits 0-5, bit 0 -> reg j.
// Wire w <-> bit (8-w):
//   wire0=wv&2, wire1=wv&1, wire2=lane&32, wire3=lane&16, wire4=lane&8,
//   wire5=lane&4, wire6=lane&2, wire7=lane&1, wire8=reg j.

template<int LM>
__device__ inline float lxor(float v){
  if constexpr (LM == 1)
    return __int_as_float(__builtin_amdgcn_mov_dpp(__float_as_int(v), 0xB1, 0xF, 0xF, true));
  else if constexpr (LM == 2)
    return __int_as_float(__builtin_amdgcn_mov_dpp(__float_as_int(v), 0x4E, 0xF, 0xF, true));
  else if constexpr (LM == 3)
    return __int_as_float(__builtin_amdgcn_mov_dpp(__float_as_int(v), 0x1B, 0xF, 0xF, true));
  else if constexpr (LM < 32)
    return __int_as_float(__builtin_amdgcn_ds_swizzle(__float_as_int(v), (LM<<10)|0x1F));
  else
    return __shfl_xor(v, LM);
}

// store both amps to LDS state image; barrier-bracketed
__device__ inline void stput(float2* sh, int i0, const float ax[2], const float ay[2]){
  __syncthreads();
  sh[i0]     = make_float2(ax[0], ay[0]);
  sh[i0 | 1] = make_float2(ax[1], ay[1]);
  __syncthreads();
}

// h_d = G[p][p^d], p = (cb<<1)|tb
__device__ inline void hsel(const float* G, bool cb, bool tb,
                            float hx[4], float hy[4]){
  const float* Gx = G; const float* Gy = G + 16;
  #pragma unroll
  for (int d = 0; d < 4; ++d){
    float xa = tb ? Gx[4+(1^d)]  : Gx[d];
    float xb = tb ? Gx[12+(3^d)] : Gx[8+(2^d)];
    float ya = tb ? Gy[4+(1^d)]  : Gy[d];
    float yb = tb ? Gy[12+(3^d)] : Gy[8+(2^d)];
    hx[d] = cb ? xb : xa;
    hy[d] = cb ? yb : ya;
  }
}

__device__ inline void cfma(float& nx, float& ny, float hx, float hy, float vx, float vy){
  nx += hx*vx - hy*vy;
  ny += hx*vy + hy*vx;
}

// both wires in lane bits
template<int LC, int LT>
__device__ inline void step_ll(float ax[2], float ay[2], int lane, const float* G){
  float hx[4], hy[4];
  hsel(G, (lane & LC) != 0, (lane & LT) != 0, hx, hy);
  #pragma unroll
  for (int j = 0; j < 2; ++j){
    float ox = ax[j], oy = ay[j];
    float tx = lxor<LT>(ox),      ty = lxor<LT>(oy);
    float cx = lxor<LC>(ox),      cy = lxor<LC>(oy);
    float bx = lxor<(LC^LT)>(ox), by = lxor<(LC^LT)>(oy);
    float nx = 0.f, ny = 0.f;
    cfma(nx,ny,hx[0],hy[0],ox,oy);
    cfma(nx,ny,hx[1],hy[1],tx,ty);
    cfma(nx,ny,hx[2],hy[2],cx,cy);
    cfma(nx,ny,hx[3],hy[3],bx,by);
    ax[j] = nx; ay[j] = ny;
  }
}

// ctrl = wv bit1 (amp bit8), tgt = wv bit0 (amp bit7)  (ent step I=0)
__device__ inline void step_ww(float ax[2], float ay[2], int i0, int wv,
                               float2* sh, const float* G){
  stput(sh, i0, ax, ay);
  float hx[4], hy[4];
  hsel(G, (wv & 2) != 0, (wv & 1) != 0, hx, hy);
  #pragma unroll
  for (int j = 0; j < 2; ++j){
    int i = i0 | j;
    float2 t = sh[i ^ 0x080];
    float2 c = sh[i ^ 0x100];
    float2 b = sh[i ^ 0x180];
    float nx = 0.f, ny = 0.f;
    cfma(nx,ny,hx[0],hy[0],ax[j],ay[j]);
    cfma(nx,ny,hx[1],hy[1],t.x,t.y);
    cfma(nx,ny,hx[2],hy[2],c.x,c.y);
    cfma(nx,ny,hx[3],hy[3],b.x,b.y);
    ax[j] = nx; ay[j] = ny;
  }
}

// ctrl = wv bit0 (amp bit7), tgt = lane&32 (amp bit6)  (ent step I=1)
__device__ inline void step_wl(float ax[2], float ay[2], int i0, int lane, int wv,
                               float2* sh, const float* G){
  stput(sh, i0, ax, ay);
  float hx[4], hy[4];
  hsel(G, (wv & 1) != 0, (lane & 32) != 0, hx, hy);
  #pragma unroll
  for (int j = 0; j < 2; ++j){
    int i = i0 | j;
    float2 c = sh[i ^ 0x080];                          // ctrl-flip (wv^1)
    float ox = ax[j], oy = ay[j];
    float tx = lxor<32>(ox),  ty = lxor<32>(oy);       // tgt-flip
    float bx = lxor<32>(c.x), by = lxor<32>(c.y);      // both
    float nx = 0.f, ny = 0.f;
    cfma(nx,ny,hx[0],hy[0],ox,oy);
    cfma(nx,ny,hx[1],hy[1],tx,ty);
    cfma(nx,ny,hx[2],hy[2],c.x,c.y);
    cfma(nx,ny,hx[3],hy[3],bx,by);
    ax[j] = nx; ay[j] = ny;
  }
}

// ctrl = lane&1 (amp bit1), tgt = reg j (amp bit0)  (ent step I=7)
__device__ inline void step_lr(float ax[2], float ay[2], int lane, const float* G){
  const float* Gx = G; const float* Gy = G + 16;
  bool cb = (lane & 1) != 0;
  float hx[2][4], hy[2][4];
  #pragma unroll
  for (int tb = 0; tb < 2; ++tb)
    #pragma unroll
    for (int d = 0; d < 4; ++d){
      int p0 = tb, p1 = 2|tb;
      hx[tb][d] = cb ? Gx[p1*4+(p1^d)] : Gx[p0*4+(p0^d)];
      hy[tb][d] = cb ? Gy[p1*4+(p1^d)] : Gy[p0*4+(p0^d)];
    }
  float nax[2], nay[2];
  #pragma unroll
  for (int j = 0; j < 2; ++j){
    float ox = ax[j],   oy = ay[j];
    float tx = ax[j^1], ty = ay[j^1];
    float cx = lxor<1>(ox), cy = lxor<1>(oy);
    float bx = lxor<1>(tx), by = lxor<1>(ty);
    float nx = 0.f, ny = 0.f;
    cfma(nx,ny,hx[j][0],hy[j][0],ox,oy);
    cfma(nx,ny,hx[j][1],hy[j][1],tx,ty);
    cfma(nx,ny,hx[j][2],hy[j][2],cx,cy);
    cfma(nx,ny,hx[j][3],hy[j][3],bx,by);
    nax[j] = nx; nay[j] = ny;
  }
  ax[0]=nax[0]; ay[0]=nay[0]; ax[1]=nax[1]; ay[1]=nay[1];
}

// ctrl = reg j (amp bit0), tgt = wv bit1 (amp bit8)  (ent step I=8)
__device__ inline void step_rw(float ax[2], float ay[2], int i0, int wv,
                               float2* sh, const float* G){
  stput(sh, i0, ax, ay);
  float2 t0 = sh[i0 ^ 0x100];
  float2 t1 = sh[(i0 ^ 0x100) | 1];
  const float* Gx = G; const float* Gy = G + 16;
  bool tb = (wv & 2) != 0;
  float hx[2][4], hy[2][4];
  #pragma unroll
  for (int cb = 0; cb < 2; ++cb)
    #pragma unroll
    for (int d = 0; d < 4; ++d){
      int p = (cb<<1) | (tb ? 1 : 0);
      hx[cb][d] = Gx[p*4+(p^d)];
      hy[cb][d] = Gy[p*4+(p^d)];
    }
  float tjx[2] = {t0.x, t1.x}, tjy[2] = {t0.y, t1.y};
  float nax[2], nay[2];
  #pragma unroll
  for (int j = 0; j < 2; ++j){
    float nx = 0.f, ny = 0.f;
    cfma(nx,ny,hx[j][0],hy[j][0],ax[j],ay[j]);      // own
    cfma(nx,ny,hx[j][1],hy[j][1],tjx[j],tjy[j]);    // tgt flip (wv^2)
    cfma(nx,ny,hx[j][2],hy[j][2],ax[j^1],ay[j^1]);  // ctrl flip (reg)
    cfma(nx,ny,hx[j][3],hy[j][3],tjx[j^1],tjy[j^1]);// both
    nax[j] = nx; nay[j] = ny;
  }
  ax[0]=nax[0]; ay[0]=nay[0]; ax[1]=nax[1]; ay[1]=nay[1];
}

// ---- Rot (1-qubit complex 2x2), u[8] = u00,u01,u10,u11 (x,y pairs) ----
template<int LM>
__device__ inline void rot_l(float ax[2], float ay[2], int lane, const float* u){
  bool hi = (lane & LM) != 0;
  float cax = hi?u[6]:u[0], cay = hi?u[7]:u[1];
  float cbx = hi?u[4]:u[2], cby = hi?u[5]:u[3];
  #pragma unroll
  for (int j = 0; j < 2; ++j){
    float ox = ax[j], oy = ay[j];
    float px = lxor<LM>(ox), py = lxor<LM>(oy);
    ax[j] = cax*ox - cay*oy + cbx*px - cby*py;
    ay[j] = cax*oy + cay*ox + cbx*py + cby*px;
  }
}

__device__ inline void rot_r(float ax[2], float ay[2], const float* u){
  float x0=ax[0], y0=ay[0], x1=ax[1], y1=ay[1];
  ax[0] = u[0]*x0 - u[1]*y0 + u[2]*x1 - u[3]*y1;
  ay[0] = u[0]*y0 + u[1]*x0 + u[2]*y1 + u[3]*x1;
  ax[1] = u[4]*x0 - u[5]*y0 + u[6]*x1 - u[7]*y1;
  ay[1] = u[4]*y0 + u[5]*x0 + u[6]*y1 + u[7]*x1;
}

template<int P>
__device__ inline void rot_w(float ax[2], float ay[2], int i0, bool hi,
                             float2* sh, const float* u){
  stput(sh, i0, ax, ay);
  float2 p0 = sh[i0 ^ P];
  float2 p1 = sh[(i0 ^ P) | 1];
  float cax = hi?u[6]:u[0], cay = hi?u[7]:u[1];
  float cbx = hi?u[4]:u[2], cby = hi?u[5]:u[3];
  float px[2] = {p0.x, p1.x}, py[2] = {p0.y, p1.y};
  #pragma unroll
  for (int j = 0; j < 2; ++j){
    float ox = ax[j], oy = ay[j];
    ax[j] = cax*ox - cay*oy + cbx*px[j] - cby*py[j];
    ay[j] = cax*oy + cay*ox + cbx*py[j] + cby*px[j];
  }
}

// CNOT ring of range R (runtime): one LDS permutation round-trip.
__device__ inline void ring_rt(float ax[2], float ay[2], int i0, float2* sh, int R){
  __syncthreads();
  sh[i0]     = make_float2(ax[0], ay[0]);
  sh[i0 | 1] = make_float2(ax[1], ay[1]);
  __syncthreads();
  #pragma unroll
  for (int j = 0; j < 2; ++j){
    int s = i0 + j;
    for (int i = 8; i >= 0; --i){
      int bc = 8 - i;
      int it = i + R; if (it >= 9) it -= 9;
      int bt = 8 - it;
      s ^= ((s >> bc) & 1) << bt;
    }
    float2 v = sh[s];
    ax[j] = v.x; ay[j] = v.y;
  }
}

// ---------------- loopable drivers (runtime coef base, I unrolled) ----------------

template<int I = 0>
__device__ inline void ent_blk(float ax[2], float ay[2], int i0, int lane, int wv,
                               float2* sh, const float* Gbase){
  const float* G = Gbase + I*32;
  if constexpr      (I == 0) step_ww(ax, ay, i0, wv, sh, G);
  else if constexpr (I == 1) step_wl(ax, ay, i0, lane, wv, sh, G);
  else if constexpr (I == 2) step_ll<32,16>(ax, ay, lane, G);
  else if constexpr (I == 3) step_ll<16, 8>(ax, ay, lane, G);
  else if constexpr (I == 4) step_ll< 8, 4>(ax, ay, lane, G);
  else if constexpr (I == 5) step_ll< 4, 2>(ax, ay, lane, G);
  else if constexpr (I == 6) step_ll< 2, 1>(ax, ay, lane, G);
  else if constexpr (I == 7) step_lr(ax, ay, lane, G);
  else                       step_rw(ax, ay, i0, wv, sh, G);
  if constexpr (I < 8) ent_blk<I+1>(ax, ay, i0, lane, wv, sh, Gbase);
}

template<int I = 0>
__device__ inline void sel_rots_rt(float ax[2], float ay[2], int i0, int lane, int wv,
                                   float2* sh, const float* ubase){
  const float* u = ubase + I*8;
  if constexpr      (I == 0) rot_w<0x100>(ax, ay, i0, (wv & 2) != 0, sh, u);
  else if constexpr (I == 1) rot_w<0x080>(ax, ay, i0, (wv & 1) != 0, sh, u);
  else if constexpr (I == 2) rot_l<32>(ax, ay, lane, u);
  else if constexpr (I == 3) rot_l<16>(ax, ay, lane, u);
  else if constexpr (I == 4) rot_l< 8>(ax, ay, lane, u);
  else if constexpr (I == 5) rot_l< 4>(ax, ay, lane, u);
  else if constexpr (I == 6) rot_l< 2>(ax, ay, lane, u);
  else if constexpr (I == 7) rot_l< 1>(ax, ay, lane, u);
  else                       rot_r(ax, ay, u);
  if constexpr (I < 8) sel_rots_rt<I+1>(ax, ay, i0, lane, wv, sh, ubase);
}

__global__ __launch_bounds__(256) void sim_V(const float* __restrict__ params,
                                             const float* __restrict__ weights,
                                             const float* __restrict__ params2,
                                             unsigned short* __restrict__ A2){
  __shared__ float2 sh[512];
  __shared__ float scoef[COEF_FLOATS];
  int tid = threadIdx.x;

  // ---- inline coefficient precompute (each block builds its own LDS table) ----
  if (tid < 72){
    int blk = tid / 9, I = tid % 9;
    const float* p = (blk < 3) ? params + blk*36 : params2 + (blk-3)*36;
    float s0,c0,s1,c1,s2,c2,s3,c3;
    __sincosf(0.5f*p[4*I+0], &s0, &c0);
    __sincosf(0.5f*p[4*I+1], &s1, &c1);
    __sincosf(0.5f*p[4*I+2], &s2, &c2);
    __sincosf(0.5f*p[4*I+3], &s3, &c3);
    float m[4][4] = {
      { c0*c1, -c0*s1, -s0*c1,  s0*s1},
      { c0*s1,  c0*c1, -s0*s1, -s0*c1},
      { s0*c1, -s0*s1,  c0*c1, -c0*s1},
      { s0*s1,  s0*c1,  c0*s1,  c0*c1}};
    float* dst = scoef + tid*32;
    #pragma unroll
    for (int q = 0; q < 4; ++q){
      dst[0*4+q]    = m[1][q];  dst[16+0*4+q] = 0.f;
      dst[1*4+q]    = m[0][q];  dst[16+1*4+q] = 0.f;
      dst[2*4+q]    =  c3*c2*m[2][q] - s3*s2*m[3][q];
      dst[16+2*4+q] =  c3*s2*m[2][q] - s3*c2*m[3][q];
      dst[3*4+q]    =  s3*s2*m[2][q] + c3*c2*m[3][q];
      dst[16+3*4+q] = -(s3*c2*m[2][q] + c3*s2*m[3][q]);
    }
  } else if (tid < 99){
    int r = tid - 72;
    int l = r / 9, i = r % 9;
    const float* w = weights + l*27 + 3*i;
    float phi = w[0], th = w[1], om = w[2];
    float sT,cT,sA,cA,sB,cB;
    __sincosf(0.5f*th, &sT, &cT);
    __sincosf(0.5f*(phi+om), &sA, &cA);
    __sincosf(0.5f*(om-phi), &sB, &cB);
    float* dst = scoef + COEF_ROT_BASE + r*8;
    dst[0] =  cA*cT;  dst[1] = -sA*cT;
    dst[2] = -cB*sT;  dst[3] =  sB*sT;
    dst[4] =  cB*sT;  dst[5] =  sB*sT;
    dst[6] =  cA*cT;  dst[7] =  sA*cT;
  }
  __syncthreads();

  int t = blockIdx.x;
  int wv = tid >> 6, lane = tid & 63;
  int i0 = tid << 1;                       // amp index of reg j=0
  float ax[2], ay[2];
  int pc = __popc((unsigned)t) & 3;
  float prx = (pc==0) ? 1.f : (pc==2 ? -1.f : 0.f);
  float pry = (pc==3) ? 1.f : (pc==1 ? -1.f : 0.f);
  #pragma unroll
  for (int j = 0; j < 2; ++j){
    bool hit = (i0 + j) == t;
    ax[j] = hit ? prx : 0.f;
    ay[j] = hit ? pry : 0.f;
  }

  #pragma unroll 1
  for (int blk = 0; blk < 3; ++blk)
    ent_blk<0>(ax, ay, i0, lane, wv, sh, scoef + blk*288);
  #pragma unroll 1
  for (int L = 0; L < 3; ++L){
    sel_rots_rt<0>(ax, ay, i0, lane, wv, sh, scoef + COEF_ROT_BASE + L*72);
    ring_rt(ax, ay, i0, sh, L + 1);
  }
  #pragma unroll 1
  for (int blk = 3; blk < 8; ++blk)
    ent_blk<0>(ax, ay, i0, lane, wv, sh, scoef + blk*288);

  #pragma unroll
  for (int j = 0; j < 2; ++j){
    int s = i0 + j;
    A2[(size_t)s * NS + t]        = f2bf(ax[j]);
    A2[(size_t)(s + NS) * NS + t] = f2bf(ay[j]);
  }
}

// build_c (wave per sample, coalesced 16B stores) + zero the output accumulator
__global__ __launch_bounds__(256) void prep(const float* __restrict__ adds,
                                            unsigned short* __restrict__ cT,
                                            float* __restrict__ out, int B){
  int gid = blockIdx.x * 256 + threadIdx.x;
  int b = gid >> 6;
  int lane = gid & 63;
  if (b < B){
    const float* ab = adds + b * NQ;
    float cw[NQ], sw[NQ];
    #pragma unroll
    for (int w = 0; w < NQ; ++w)
      __sincosf(0.5f * ab[w], &sw[w], &cw[w]);
    float p6 = 1.f;
    #pragma unroll
    for (int w = 0; w < 6; ++w)
      p6 *= ((lane >> (5 - w)) & 1) ? sw[w] : cw[w];
    union { unsigned short u[8]; uint4 v; } pk;
    #pragma unroll
    for (int j = 0; j < 8; ++j){
      float p = p6 * (((j>>2)&1) ? sw[6] : cw[6])
                   * (((j>>1)&1) ? sw[7] : cw[7])
                   * (( j    &1) ? sw[8] : cw[8]);
      pk.u[j] = f2bf(p);
    }
    *(uint4*)(cT + (size_t)b * NS + lane*8) = pk.v;
  }
  if (gid < B) out[gid] = 0.f;
}

// Phi2 = A2(1024x512) @ c(512xB); out[b] = sum_row sign(row) * Phi2[row][b]^2,
// sign(row) = -1 iff (row & 256).
__global__ __launch_bounds__(256) void gemm_out(const unsigned short* __restrict__ A2,
                                                const unsigned short* __restrict__ cT,
                                                float* __restrict__ out){
  int bx = blockIdx.x;            // N tile (128 cols of b)
  int by = blockIdx.y;            // M tile (128 rows), 8 tiles
  int tid = threadIdx.x;
  int wave = tid >> 6, lane = tid & 63;
  int wy = wave >> 1, wx = wave & 1;
  int lane15 = lane & 15, quad = lane >> 4;
  int rowBase = by*128 + wy*64;
  int colBase = bx*128 + wx*64;
  const short* Ap = (const short*)A2;   // [row][k]
  const short* Bp = (const short*)cT;   // [col][k]

  f32x4 acc[4][4];
  #pragma unroll
  for (int i = 0; i < 4; ++i)
    #pragma unroll
    for (int j = 0; j < 4; ++j)
      acc[i][j] = (f32x4){0.f, 0.f, 0.f, 0.f};

  #pragma unroll 2
  for (int k0 = 0; k0 < NS; k0 += 32){
    bf16x8 a[4], b[4];
    #pragma unroll
    for (int mi = 0; mi < 4; ++mi)
      a[mi] = *(const bf16x8*)(Ap + (size_t)(rowBase + mi*16 + lane15)*NS + k0 + quad*8);
    #pragma unroll
    for (int ni = 0; ni < 4; ++ni)
      b[ni] = *(const bf16x8*)(Bp + (size_t)(colBase + ni*16 + lane15)*NS + k0 + quad*8);
    #pragma unroll
    for (int mi = 0; mi < 4; ++mi)
      #pragma unroll
      for (int ni = 0; ni < 4; ++ni)
        acc[mi][ni] = __builtin_amdgcn_mfma_f32_16x16x32_bf16(a[mi], b[ni], acc[mi][ni], 0, 0, 0);
  }

  float sign = (by & 2) ? -1.f : 1.f;
  #pragma unroll
  for (int ni = 0; ni < 4; ++ni){
    float cs = 0.f;
    #pragma unroll
    for (int mi = 0; mi < 4; ++mi)
      #pragma unroll
      for (int r = 0; r < 4; ++r)
        cs += acc[mi][ni][r] * acc[mi][ni][r];
    cs += __shfl_xor(cs, 16);
    cs += __shfl_xor(cs, 32);
    if (quad == 0)
      atomicAdd(out + colBase + ni*16 + lane15, sign * cs);
  }
}

extern "C" void kernel_launch(void* const* d_in, const int* in_sizes, int n_in,
                              void* d_out, int out_size, void* d_ws, size_t ws_size,
                              hipStream_t stream) {
  const float* adds    = (const float*)d_in[0];
  const float* params  = (const float*)d_in[1];
  const float* weights = (const float*)d_in[2];
  const float* params2 = (const float*)d_in[3];
  float* out = (float*)d_out;
  int B = in_sizes[0] / NQ;   // 8192

  unsigned short* A2 = (unsigned short*)d_ws;        // 1024*512 bf16 = 1 MB
  unsigned short* cT = A2 + (size_t)M2 * NS;         // B*512 bf16 = 8 MB

  hipLaunchKernelGGL(sim_V, dim3(NS), dim3(256), 0, stream, params, weights, params2, A2);
  hipLaunchKernelGGL(prep, dim3((B * 64 + 255) / 256), dim3(256), 0, stream, adds, cT, out, B);
  hipLaunchKernelGGL(gemm_out, dim3(B / 128, 8), dim3(256), 0, stream, A2, cT, out);
}

// Round 8
// 119.889 us; speedup vs baseline: 1.2590x; 1.0541x over previous
//
#include <hip/hip_runtime.h>

#define NQ 9
#define NS 512            // 2^9 amplitudes
#define M2 1024           // [Re V; Im V] stacked rows

#define COEF_ROT_BASE (72*32)                 // 72 ent steps x 32 floats
#define COEF_FLOATS   (COEF_ROT_BASE + 27*8)  // + 27 rots x 8 floats = 2520

typedef __attribute__((ext_vector_type(8))) short bf16x8;
typedef __attribute__((ext_vector_type(4))) float f32x4;

__device__ inline unsigned short f2bf(float f){
  unsigned int u = __float_as_uint(f);
  u += 0x7fffu + ((u >> 16) & 1u);   // round-to-nearest-even
  return (unsigned short)(u >> 16);
}

// =====================  8-wave, 1-amp-per-lane statevector sim  =====================
// One block (8 waves, 512 thr) per column t. Thread tid holds amp index i = tid:
//   bits 0-5 -> lane, bits 6-8 -> wave id.
// Wire w <-> amp bit (8-w). Wires 0,1,2 are wave bits (LDS exchange);
// wires 3-8 are lane bits (ds_swizzle / DPP / shfl).

template<int LM>
__device__ inline float lxor(float v){
  if constexpr (LM == 1)
    return __int_as_float(__builtin_amdgcn_mov_dpp(__float_as_int(v), 0xB1, 0xF, 0xF, true));
  else if constexpr (LM == 2)
    return __int_as_float(__builtin_amdgcn_mov_dpp(__float_as_int(v), 0x4E, 0xF, 0xF, true));
  else if constexpr (LM == 3)
    return __int_as_float(__builtin_amdgcn_mov_dpp(__float_as_int(v), 0x1B, 0xF, 0xF, true));
  else if constexpr (LM < 32)
    return __int_as_float(__builtin_amdgcn_ds_swizzle(__float_as_int(v), (LM<<10)|0x1F));
  else
    return __shfl_xor(v, LM);
}

// 16 complex FMA from pre-permuted H (Hx[p][d]=Gx[p][p^d]): n = h0*o + h1*t + h2*c + h3*b
__device__ inline void apply_h(float& ax, float& ay, int p, const float* H,
                               float tx, float ty, float cx, float cy,
                               float bx, float by){
  const float* hx = H + p*4;
  const float* hy = H + 16 + p*4;
  float ox = ax, oy = ay;
  float nx = hx[0]*ox - hy[0]*oy + hx[1]*tx - hy[1]*ty
           + hx[2]*cx - hy[2]*cy + hx[3]*bx - hy[3]*by;
  float ny = hx[0]*oy + hy[0]*ox + hx[1]*ty + hy[1]*tx
           + hx[2]*cy + hy[2]*cx + hx[3]*by + hy[3]*bx;
  ax = nx; ay = ny;
}

// 2q step, ctrl/tgt amp-bit masks CM/TM; at least one is a wave bit -> LDS partners
template<int CM, int TM>
__device__ inline void step_lds(float& ax, float& ay, int i, float2* sh, const float* H){
  __syncthreads();
  sh[i] = make_float2(ax, ay);
  __syncthreads();
  float2 tv = sh[i ^ TM];
  float2 cv = sh[i ^ CM];
  float2 bv = sh[i ^ (CM ^ TM)];
  int p = ((i & CM) ? 2 : 0) | ((i & TM) ? 1 : 0);
  apply_h(ax, ay, p, H, tv.x, tv.y, cv.x, cv.y, bv.x, bv.y);
}

// 2q step, both wires in lane bits -> pure cross-lane
template<int CM, int TM>
__device__ inline void step_swz(float& ax, float& ay, int lane, const float* H){
  float tx = lxor<TM>(ax),      ty = lxor<TM>(ay);
  float cx = lxor<CM>(ax),      cy = lxor<CM>(ay);
  float bx = lxor<(CM^TM)>(ax), by = lxor<(CM^TM)>(ay);
  int p = ((lane & CM) ? 2 : 0) | ((lane & TM) ? 1 : 0);
  apply_h(ax, ay, p, H, tx, ty, cx, cy, bx, by);
}

// Rot on a wave-bit wire (amp-bit mask PM): LDS partner
template<int PM>
__device__ inline void rot_lds(float& ax, float& ay, int i, float2* sh, const float* U){
  __syncthreads();
  sh[i] = make_float2(ax, ay);
  __syncthreads();
  float2 pv = sh[i ^ PM];
  const float* u = U + (((i & PM) ? 1 : 0) << 2);
  float nx = u[0]*ax - u[1]*ay + u[2]*pv.x - u[3]*pv.y;
  float ny = u[0]*ay + u[1]*ax + u[2]*pv.y + u[3]*pv.x;
  ax = nx; ay = ny;
}

// Rot on a lane-bit wire
template<int LM>
__device__ inline void rot_swz(float& ax, float& ay, int lane, const float* U){
  float px = lxor<LM>(ax), py = lxor<LM>(ay);
  const float* u = U + (((lane & LM) ? 1 : 0) << 2);
  float nx = u[0]*ax - u[1]*ay + u[2]*px - u[3]*py;
  float ny = u[0]*ay + u[1]*ax + u[2]*py + u[3]*px;
  ax = nx; ay = ny;
}

// CNOT ring of range R (runtime): one LDS permutation round-trip.
__device__ inline void ring_rt(float& ax, float& ay, int i, float2* sh, int R){
  __syncthreads();
  sh[i] = make_float2(ax, ay);
  __syncthreads();
  int s = i;
  for (int k = 8; k >= 0; --k){
    int bc = 8 - k;
    int it = k + R; if (it >= 9) it -= 9;
    int bt = 8 - it;
    s ^= ((s >> bc) & 1) << bt;
  }
  float2 v = sh[s];
  ax = v.x; ay = v.y;
}

// ---------------- loopable drivers (runtime coef base, I unrolled) ----------------

template<int I = 0>
__device__ inline void ent_blk(float& ax, float& ay, int i, int lane, float2* sh,
                               const float* Gbase){
  const float* H = Gbase + I*32;
  if constexpr      (I == 0) step_lds<0x100,0x080>(ax, ay, i, sh, H);
  else if constexpr (I == 1) step_lds<0x080,0x040>(ax, ay, i, sh, H);
  else if constexpr (I == 2) step_lds<0x040,0x020>(ax, ay, i, sh, H);
  else if constexpr (I == 3) step_swz<0x20,0x10>(ax, ay, lane, H);
  else if constexpr (I == 4) step_swz<0x10,0x08>(ax, ay, lane, H);
  else if constexpr (I == 5) step_swz<0x08,0x04>(ax, ay, lane, H);
  else if constexpr (I == 6) step_swz<0x04,0x02>(ax, ay, lane, H);
  else if constexpr (I == 7) step_swz<0x02,0x01>(ax, ay, lane, H);
  else                       step_lds<0x001,0x100>(ax, ay, i, sh, H);
  if constexpr (I < 8) ent_blk<I+1>(ax, ay, i, lane, sh, Gbase);
}

template<int I = 0>
__device__ inline void sel_rots_rt(float& ax, float& ay, int i, int lane, float2* sh,
                                   const float* ubase){
  const float* u = ubase + I*8;
  if constexpr      (I == 0) rot_lds<0x100>(ax, ay, i, sh, u);
  else if constexpr (I == 1) rot_lds<0x080>(ax, ay, i, sh, u);
  else if constexpr (I == 2) rot_lds<0x040>(ax, ay, i, sh, u);
  else if constexpr (I == 3) rot_swz<0x20>(ax, ay, lane, u);
  else if constexpr (I == 4) rot_swz<0x10>(ax, ay, lane, u);
  else if constexpr (I == 5) rot_swz<0x08>(ax, ay, lane, u);
  else if constexpr (I == 6) rot_swz<0x04>(ax, ay, lane, u);
  else if constexpr (I == 7) rot_swz<0x02>(ax, ay, lane, u);
  else                       rot_swz<0x01>(ax, ay, lane, u);
  if constexpr (I < 8) sel_rots_rt<I+1>(ax, ay, i, lane, sh, ubase);
}

__global__ __launch_bounds__(512) void sim_V(const float* __restrict__ params,
                                             const float* __restrict__ weights,
                                             const float* __restrict__ params2,
                                             unsigned short* __restrict__ A2){
  __shared__ float2 sh[512];
  __shared__ float scoef[COEF_FLOATS];
  int tid = threadIdx.x;

  // ---- inline coefficient precompute: ent H (pre-permuted) + rot U ----
  if (tid < 72){
    int blk = tid / 9, I = tid % 9;
    const float* p = (blk < 3) ? params + blk*36 : params2 + (blk-3)*36;
    float s0,c0,s1,c1,s2,c2,s3,c3;
    __sincosf(0.5f*p[4*I+0], &s0, &c0);
    __sincosf(0.5f*p[4*I+1], &s1, &c1);
    __sincosf(0.5f*p[4*I+2], &s2, &c2);
    __sincosf(0.5f*p[4*I+3], &s3, &c3);
    float m[4][4] = {
      { c0*c1, -c0*s1, -s0*c1,  s0*s1},
      { c0*s1,  c0*c1, -s0*s1, -s0*c1},
      { s0*c1, -s0*s1,  c0*c1, -c0*s1},
      { s0*s1,  s0*c1,  c0*s1,  c0*c1}};
    float gx[4][4], gy[4][4];
    #pragma unroll
    for (int q = 0; q < 4; ++q){
      gx[0][q] = m[1][q];  gy[0][q] = 0.f;      // row swap from X(q_target)
      gx[1][q] = m[0][q];  gy[1][q] = 0.f;
      gx[2][q] =  c3*c2*m[2][q] - s3*s2*m[3][q];
      gy[2][q] =  c3*s2*m[2][q] - s3*c2*m[3][q];
      gx[3][q] =  s3*s2*m[2][q] + c3*c2*m[3][q];
      gy[3][q] = -(s3*c2*m[2][q] + c3*s2*m[3][q]);
    }
    float* dst = scoef + tid*32;
    #pragma unroll
    for (int pp = 0; pp < 4; ++pp)
      #pragma unroll
      for (int d = 0; d < 4; ++d){
        dst[pp*4+d]    = gx[pp][pp^d];   // Hx[p][d] = Gx[p][p^d]
        dst[16+pp*4+d] = gy[pp][pp^d];
      }
  } else if (tid < 99){
    int r = tid - 72;
    int l = r / 9, i = r % 9;
    const float* w = weights + l*27 + 3*i;
    float phi = w[0], th = w[1], om = w[2];
    float sT,cT,sA,cA,sB,cB;
    __sincosf(0.5f*th, &sT, &cT);
    __sincosf(0.5f*(phi+om), &sA, &cA);
    __sincosf(0.5f*(om-phi), &sB, &cB);
    float* dst = scoef + COEF_ROT_BASE + r*8;
    dst[0] =  cA*cT;  dst[1] = -sA*cT;   // side 0: u00 (diag), u01 (off)
    dst[2] = -cB*sT;  dst[3] =  sB*sT;
    dst[4] =  cA*cT;  dst[5] =  sA*cT;   // side 1: u11 (diag), u10 (off)
    dst[6] =  cB*sT;  dst[7] =  sB*sT;
  }
  __syncthreads();

  int t = blockIdx.x;
  int i = tid;                 // amp index
  int lane = tid & 63;
  float ax, ay;
  int pc = __popc((unsigned)t) & 3;
  float prx = (pc==0) ? 1.f : (pc==2 ? -1.f : 0.f);
  float pry = (pc==3) ? 1.f : (pc==1 ? -1.f : 0.f);
  ax = (i == t) ? prx : 0.f;
  ay = (i == t) ? pry : 0.f;

  #pragma unroll 1
  for (int blk = 0; blk < 3; ++blk)
    ent_blk<0>(ax, ay, i, lane, sh, scoef + blk*288);
  #pragma unroll 1
  for (int L = 0; L < 3; ++L){
    sel_rots_rt<0>(ax, ay, i, lane, sh, scoef + COEF_ROT_BASE + L*72);
    ring_rt(ax, ay, i, sh, L + 1);
  }
  #pragma unroll 1
  for (int blk = 3; blk < 8; ++blk)
    ent_blk<0>(ax, ay, i, lane, sh, scoef + blk*288);

  A2[(size_t)i * NS + t]        = f2bf(ax);
  A2[(size_t)(i + NS) * NS + t] = f2bf(ay);
}

// build_c (wave per sample, coalesced 16B stores) + zero the output accumulator
__global__ __launch_bounds__(256) void prep(const float* __restrict__ adds,
                                            unsigned short* __restrict__ cT,
                                            float* __restrict__ out, int B){
  int gid = blockIdx.x * 256 + threadIdx.x;
  int b = gid >> 6;
  int lane = gid & 63;
  if (b < B){
    const float* ab = adds + b * NQ;
    float cw[NQ], sw[NQ];
    #pragma unroll
    for (int w = 0; w < NQ; ++w)
      __sincosf(0.5f * ab[w], &sw[w], &cw[w]);
    float p6 = 1.f;
    #pragma unroll
    for (int w = 0; w < 6; ++w)
      p6 *= ((lane >> (5 - w)) & 1) ? sw[w] : cw[w];
    union { unsigned short u[8]; uint4 v; } pk;
    #pragma unroll
    for (int j = 0; j < 8; ++j){
      float p = p6 * (((j>>2)&1) ? sw[6] : cw[6])
                   * (((j>>1)&1) ? sw[7] : cw[7])
                   * (( j    &1) ? sw[8] : cw[8]);
      pk.u[j] = f2bf(p);
    }
    *(uint4*)(cT + (size_t)b * NS + lane*8) = pk.v;
  }
  if (gid < B) out[gid] = 0.f;
}

// Phi2 = A2(1024x512) @ c(512xB); out[b] = sum_row sign(row) * Phi2[row][b]^2,
// sign(row) = -1 iff (row & 256).
__global__ __launch_bounds__(256) void gemm_out(const unsigned short* __restrict__ A2,
                                                const unsigned short* __restrict__ cT,
                                                float* __restrict__ out){
  int bx = blockIdx.x;            // N tile (128 cols of b)
  int by = blockIdx.y;            // M tile (128 rows), 8 tiles
  int tid = threadIdx.x;
  int wave = tid >> 6, lane = tid & 63;
  int wy = wave >> 1, wx = wave & 1;
  int lane15 = lane & 15, quad = lane >> 4;
  int rowBase = by*128 + wy*64;
  int colBase = bx*128 + wx*64;
  const short* Ap = (const short*)A2;   // [row][k]
  const short* Bp = (const short*)cT;   // [col][k]

  f32x4 acc[4][4];
  #pragma unroll
  for (int i = 0; i < 4; ++i)
    #pragma unroll
    for (int j = 0; j < 4; ++j)
      acc[i][j] = (f32x4){0.f, 0.f, 0.f, 0.f};

  #pragma unroll 2
  for (int k0 = 0; k0 < NS; k0 += 32){
    bf16x8 a[4], b[4];
    #pragma unroll
    for (int mi = 0; mi < 4; ++mi)
      a[mi] = *(const bf16x8*)(Ap + (size_t)(rowBase + mi*16 + lane15)*NS + k0 + quad*8);
    #pragma unroll
    for (int ni = 0; ni < 4; ++ni)
      b[ni] = *(const bf16x8*)(Bp + (size_t)(colBase + ni*16 + lane15)*NS + k0 + quad*8);
    #pragma unroll
    for (int mi = 0; mi < 4; ++mi)
      #pragma unroll
      for (int ni = 0; ni < 4; ++ni)
        acc[mi][ni] = __builtin_amdgcn_mfma_f32_16x16x32_bf16(a[mi], b[ni], acc[mi][ni], 0, 0, 0);
  }

  float sign = (by & 2) ? -1.f : 1.f;
  #pragma unroll
  for (int ni = 0; ni < 4; ++ni){
    float cs = 0.f;
    #pragma unroll
    for (int mi = 0; mi < 4; ++mi)
      #pragma unroll
      for (int r = 0; r < 4; ++r)
        cs += acc[mi][ni][r] * acc[mi][ni][r];
    cs += __shfl_xor(cs, 16);
    cs += __shfl_xor(cs, 32);
    if (quad == 0)
      atomicAdd(out + colBase + ni*16 + lane15, sign * cs);
  }
}

extern "C" void kernel_launch(void* const* d_in, const int* in_sizes, int n_in,
                              void* d_out, int out_size, void* d_ws, size_t ws_size,
                              hipStream_t stream) {
  const float* adds    = (const float*)d_in[0];
  const float* params  = (const float*)d_in[1];
  const float* weights = (const float*)d_in[2];
  const float* params2 = (const float*)d_in[3];
  float* out = (float*)d_out;
  int B = in_sizes[0] / NQ;   // 8192

  unsigned short* A2 = (unsigned short*)d_ws;        // 1024*512 bf16 = 1 MB
  unsigned short* cT = A2 + (size_t)M2 * NS;         // B*512 bf16 = 8 MB

  hipLaunchKernelGGL(sim_V, dim3(NS), dim3(512), 0, stream, params, weights, params2, A2);
  hipLaunchKernelGGL(prep, dim3((B * 64 + 255) / 256), dim3(256), 0, stream, adds, cT, out, B);
  hipLaunchKernelGGL(gemm_out, dim3(B / 128, 8), dim3(256), 0, stream, A2, cT, out);
}